// Round 8
// baseline (1329.950 us; speedup 1.0000x reference)
//
#include <hip/hip_runtime.h>

#define U_NUM 359347
#define I_NUM 292589
#define DDIM  64
#define NNZ_N 4000000
#define BATCH 32768
#define LAM_F 0.001f
#define ACC_SLOTS 2048

#define EPB   4096                          // edges per level-1 block
#define NBLK  ((NNZ_N + EPB - 1) / EPB)     // 977
#define NB_U  ((U_NUM + 1023) >> 10)        // 351
#define NB_I  ((I_NUM + 1023) >> 10)        // 286

__device__ __forceinline__ float leaky(float x) { return x > 0.f ? x : 0.1f * x; }

__device__ __forceinline__ unsigned short f2bf(float f) {
    unsigned b = __float_as_uint(f);
    b = (b + 0x7FFF + ((b >> 16) & 1)) >> 16;   // RNE
    return (unsigned short)b;
}
__device__ __forceinline__ float bf2f(unsigned short u) {
    return __uint_as_float((unsigned)u << 16);
}
__device__ __forceinline__ float bflo(unsigned u) { return __uint_as_float(u << 16); }
__device__ __forceinline__ float bfhi(unsigned u) { return __uint_as_float(u & 0xffff0000u); }

// ---- fp8 e4m3fn with global scale 64 folded into encode/decode ----
__device__ __forceinline__ unsigned char f2fp8(float v) {
    v = fminf(fmaxf(v * 64.f, -440.f), 440.f);
    unsigned b = __float_as_uint(v * 0x1p-120f);
    unsigned sign = (b >> 24) & 0x80u;
    unsigned mag = b & 0x7fffffffu;
    mag += 0x7ffffu + ((mag >> 20) & 1u);        // RNE to 3 mantissa bits
    return (unsigned char)(sign | ((mag >> 20) & 0x7fu));
}
__device__ __forceinline__ float fp82f(unsigned char c) {
    unsigned u = c;
    float f = __uint_as_float(((u & 0x80u) << 24) | ((u & 0x7fu) << 20));
    return f * 0x1p114f;                          // 2^120 / 64
}

// ---------------------------------------------------------------------------
// fp32 -> bf16 + fp8 bulk convert
// ---------------------------------------------------------------------------
__global__ __launch_bounds__(256) void f2bf8_k(
    const float4* __restrict__ in, ushort4* __restrict__ outb,
    uchar4* __restrict__ out8, size_t n4)
{
    size_t stride = (size_t)gridDim.x * 256;
    for (size_t i = (size_t)blockIdx.x * 256 + threadIdx.x; i < n4; i += stride) {
        float4 v = in[i];
        ushort4 o;
        o.x = f2bf(v.x); o.y = f2bf(v.y); o.z = f2bf(v.z); o.w = f2bf(v.w);
        outb[i] = o;
        uchar4 p;
        p.x = f2fp8(v.x); p.y = f2fp8(v.y); p.z = f2fp8(v.z); p.w = f2fp8(v.w);
        out8[i] = p;
    }
}

// ---------------------------------------------------------------------------
// Level-1: bucket histogram per block  (bucket = key >> 10)
// ---------------------------------------------------------------------------
__global__ __launch_bounds__(256) void l1hist_k(
    const int* __restrict__ keys, int* __restrict__ gh, int nb)
{
    __shared__ int h[512];
    for (int i = threadIdx.x; i < nb; i += 256) h[i] = 0;
    __syncthreads();
    int base = blockIdx.x * EPB;
    int end = min(base + EPB, NNZ_N);
    for (int e = base + threadIdx.x; e < end; e += 256)
        atomicAdd(&h[keys[e] >> 10], 1);
    __syncthreads();
    for (int i = threadIdx.x; i < nb; i += 256)
        gh[i * NBLK + blockIdx.x] = h[i];
}

__global__ __launch_bounds__(256) void scan1_k(int* __restrict__ a, int n, int* __restrict__ bsum)
{
    __shared__ int s[256];
    int t = threadIdx.x;
    int base = blockIdx.x * 1024 + t * 4;
    int v[4];
#pragma unroll
    for (int j = 0; j < 4; ++j) v[j] = (base + j < n) ? a[base + j] : 0;
    s[t] = v[0] + v[1] + v[2] + v[3];
    __syncthreads();
    for (int off = 1; off < 256; off <<= 1) {
        int x = (t >= off) ? s[t - off] : 0;
        __syncthreads();
        s[t] += x;
        __syncthreads();
    }
    if (t == 255) bsum[blockIdx.x] = s[255];
    int run = (t > 0) ? s[t - 1] : 0;
#pragma unroll
    for (int j = 0; j < 4; ++j) {
        if (base + j < n) a[base + j] = run;
        run += v[j];
    }
}

__global__ __launch_bounds__(512) void scan2_k(int* __restrict__ bsum, int nb)
{
    __shared__ int s[512];
    int t = threadIdx.x;
    int v = (t < nb) ? bsum[t] : 0;
    s[t] = v;
    __syncthreads();
    for (int off = 1; off < 512; off <<= 1) {
        int x = (t >= off) ? s[t - off] : 0;
        __syncthreads();
        s[t] += x;
        __syncthreads();
    }
    if (t < nb) bsum[t] = s[t] - v;   // exclusive
}

__global__ __launch_bounds__(256) void scan3_k(int* __restrict__ a, int n,
                                               const int* __restrict__ bsum)
{
    int add = bsum[blockIdx.x];
    int base = blockIdx.x * 1024 + threadIdx.x * 4;
#pragma unroll
    for (int j = 0; j < 4; ++j)
        if (base + j < n) a[base + j] += add;
}

__global__ __launch_bounds__(256) void l1scatter_k(
    const int* __restrict__ keys, const int* __restrict__ gh, int nb,
    int2* __restrict__ out)
{
    __shared__ int cur[512];
    for (int i = threadIdx.x; i < nb; i += 256) cur[i] = gh[i * NBLK + blockIdx.x];
    __syncthreads();
    int base = blockIdx.x * EPB;
    int end = min(base + EPB, NNZ_N);
    for (int e = base + threadIdx.x; e < end; e += 256) {
        int k = keys[e];
        int pos = atomicAdd(&cur[k >> 10], 1);
        out[pos] = make_int2(k, e);
    }
}

// Level-2: LDS counting sort per bucket; emits ptr and split (col, bf16 val)
__global__ __launch_bounds__(256) void l2sort_k(
    const int2* __restrict__ tmp, const int* __restrict__ gh, int nb,
    const int* __restrict__ colArr, const float* __restrict__ valArr,
    int* __restrict__ ptr, int nrows,
    int* __restrict__ ecol, unsigned short* __restrict__ eval)
{
    __shared__ int hist[1024];
    __shared__ int ssc[256];
    int b = blockIdx.x;
    int t = threadIdx.x;
    int bucket_base = gh[b * NBLK];
    int bucket_end  = (b == nb - 1) ? NNZ_N : gh[(b + 1) * NBLK];
    for (int i = t; i < 1024; i += 256) hist[i] = 0;
    __syncthreads();
    for (int e = bucket_base + t; e < bucket_end; e += 256)
        atomicAdd(&hist[tmp[e].x & 1023], 1);
    __syncthreads();
    int v0 = hist[t * 4], v1 = hist[t * 4 + 1], v2 = hist[t * 4 + 2], v3 = hist[t * 4 + 3];
    ssc[t] = v0 + v1 + v2 + v3;
    __syncthreads();
    for (int off = 1; off < 256; off <<= 1) {
        int x = (t >= off) ? ssc[t - off] : 0;
        __syncthreads();
        ssc[t] += x;
        __syncthreads();
    }
    int run = (t > 0) ? ssc[t - 1] : 0;
    int g0 = run, g1 = run + v0, g2 = g1 + v1, g3 = g2 + v2;
    hist[t * 4] = g0; hist[t * 4 + 1] = g1; hist[t * 4 + 2] = g2; hist[t * 4 + 3] = g3;
    int rbase = b << 10;
    if (rbase + t * 4 < nrows)     ptr[rbase + t * 4]     = bucket_base + g0;
    if (rbase + t * 4 + 1 < nrows) ptr[rbase + t * 4 + 1] = bucket_base + g1;
    if (rbase + t * 4 + 2 < nrows) ptr[rbase + t * 4 + 2] = bucket_base + g2;
    if (rbase + t * 4 + 3 < nrows) ptr[rbase + t * 4 + 3] = bucket_base + g3;
    if (b == nb - 1 && t == 0) ptr[nrows] = NNZ_N;
    __syncthreads();
    for (int e = bucket_base + t; e < bucket_end; e += 256) {
        int2 q = tmp[e];
        int pos = bucket_base + atomicAdd(&hist[q.x & 1023], 1);
        ecol[pos] = colArr[q.y];
        eval[pos] = f2bf(valArr[q.y]);
    }
}

// ---------------------------------------------------------------------------
// CSR SpMM: gathers fp8 rows (64 B/edge), streams bf16.
// MODE 0: o = relu(A@x + base*deg); write bf16 + fp8 copies.
// MODE 1: o = relu(A@x + base*deg); out = w0*embed + w1*base + w2*o (bf16);
//         accumulate sum(out^2).  base/out and embed/out may alias.
// ---------------------------------------------------------------------------
template <int MODE>
__global__ __launch_bounds__(256) void spmm_csr_k(
    const int* __restrict__ ptr, const int* __restrict__ ecol,
    const unsigned short* __restrict__ eval,
    const unsigned char* __restrict__ x8, const unsigned short* base,
    const float* __restrict__ deg, unsigned short* out, int nrows,
    unsigned char* __restrict__ out8,
    const unsigned short* embed, const float* __restrict__ add_w,
    float* __restrict__ accArr)
{
    int wv = threadIdx.x >> 6, lane = threadIdx.x & 63;
    int r = blockIdx.x * 4 + wv;
    __shared__ float ssum[4];
    if (r < nrows) {
        int s0 = __builtin_amdgcn_readfirstlane(ptr[r]);
        int e0 = __builtin_amdgcn_readfirstlane(ptr[r + 1]);
        float a0 = 0.f, a1 = 0.f, a2 = 0.f, a3 = 0.f;
        int k = s0;
        for (; k + 4 <= e0; k += 4) {
            int c0 = ecol[k], c1 = ecol[k + 1], c2 = ecol[k + 2], c3 = ecol[k + 3];
            float v0 = bf2f(eval[k]),     v1 = bf2f(eval[k + 1]);
            float v2 = bf2f(eval[k + 2]), v3 = bf2f(eval[k + 3]);
            float x0 = fp82f(x8[(size_t)c0 * DDIM + lane]);
            float x1 = fp82f(x8[(size_t)c1 * DDIM + lane]);
            float x2 = fp82f(x8[(size_t)c2 * DDIM + lane]);
            float x3 = fp82f(x8[(size_t)c3 * DDIM + lane]);
            a0 = fmaf(v0, x0, a0);
            a1 = fmaf(v1, x1, a1);
            a2 = fmaf(v2, x2, a2);
            a3 = fmaf(v3, x3, a3);
        }
        for (; k < e0; ++k)
            a0 = fmaf(bf2f(eval[k]), fp82f(x8[(size_t)ecol[k] * DDIM + lane]), a0);
        float acc = (a0 + a1) + (a2 + a3);
        float bb = bf2f(base[(size_t)r * DDIM + lane]);
        float o = fmaxf(fmaf(bb, deg[r], acc), 0.f);
        if (MODE == 0) {
            out[(size_t)r * DDIM + lane] = f2bf(o);
            out8[(size_t)r * DDIM + lane] = f2fp8(o);
        } else {
            float g = fmaf(add_w[0], bf2f(embed[(size_t)r * DDIM + lane]),
                           fmaf(add_w[1], bb, add_w[2] * o));
            out[(size_t)r * DDIM + lane] = f2bf(g);
            float sq = g * g;
            for (int off = 32; off; off >>= 1) sq += __shfl_down(sq, off);
            if (lane == 0) ssum[wv] = sq;
        }
    } else if (MODE == 1) {
        if (lane == 0) ssum[wv] = 0.f;
    }
    if (MODE == 1) {
        __syncthreads();
        if (threadIdx.x == 0)
            atomicAdd(&accArr[blockIdx.x & (ACC_SLOTS - 1)],
                      ssum[0] + ssum[1] + ssum[2] + ssum[3]);
    }
}

// ---------------------------------------------------------------------------
// MLP as block-tiled VALU GEMM (unchanged from round 7)
// ---------------------------------------------------------------------------
__global__ __launch_bounds__(256) void mlp_k(
    const int* __restrict__ user0, const int* __restrict__ item0,
    const unsigned short* __restrict__ gcnU, const unsigned short* __restrict__ gcnI,
    const float* __restrict__ fw1, const float* __restrict__ fb1,
    const float* __restrict__ fw2, const float* __restrict__ fb2,
    unsigned short* __restrict__ ou, unsigned short* __restrict__ oi)
{
    __shared__ unsigned short xs[64][72];
    __shared__ unsigned short w1s[128][68];
    __shared__ unsigned short w2s[64][140];
    __shared__ unsigned short hs[128][72];
    __shared__ float b1s[128];
    __shared__ float b2s[64];

    int t = threadIdx.x;
    int side = blockIdx.x >> 9;
    int tile = blockIdx.x & 511;
    const int* sel = side ? item0 : user0;
    const unsigned short* gcn = side ? gcnI : gcnU;
    unsigned short* outp = side ? oi : ou;

    {
        int r = t >> 2, c = t & 3;
        int idx = sel[tile * 64 + r];
        const ushort4* src = (const ushort4*)(gcn + (size_t)idx * 64 + c * 16);
        ushort4 v0 = src[0], v1 = src[1], v2 = src[2], v3 = src[3];
        int k0 = c * 16;
        xs[k0 +  0][r] = v0.x; xs[k0 +  1][r] = v0.y; xs[k0 +  2][r] = v0.z; xs[k0 +  3][r] = v0.w;
        xs[k0 +  4][r] = v1.x; xs[k0 +  5][r] = v1.y; xs[k0 +  6][r] = v1.z; xs[k0 +  7][r] = v1.w;
        xs[k0 +  8][r] = v2.x; xs[k0 +  9][r] = v2.y; xs[k0 + 10][r] = v2.z; xs[k0 + 11][r] = v2.w;
        xs[k0 + 12][r] = v3.x; xs[k0 + 13][r] = v3.y; xs[k0 + 14][r] = v3.z; xs[k0 + 15][r] = v3.w;
    }
#pragma unroll
    for (int i = 0; i < 8; ++i) {
        int flat = i * 1024 + t * 4;
        float4 w = *(const float4*)(fw1 + flat);
        int o = flat >> 6, k = flat & 63;
        *(unsigned*)&w1s[o][k]     = (unsigned)f2bf(w.x) | ((unsigned)f2bf(w.y) << 16);
        *(unsigned*)&w1s[o][k + 2] = (unsigned)f2bf(w.z) | ((unsigned)f2bf(w.w) << 16);
        float4 u = *(const float4*)(fw2 + flat);
        int o2 = flat >> 7, k2 = flat & 127;
        *(unsigned*)&w2s[o2][k2]     = (unsigned)f2bf(u.x) | ((unsigned)f2bf(u.y) << 16);
        *(unsigned*)&w2s[o2][k2 + 2] = (unsigned)f2bf(u.z) | ((unsigned)f2bf(u.w) << 16);
    }
    if (t < 128) b1s[t] = fb1[t];
    if (t < 64)  b2s[t] = fb2[t];
    __syncthreads();

    int sg = t & 15, og = t >> 4;

    float acc[4][8];
#pragma unroll
    for (int i = 0; i < 4; ++i)
#pragma unroll
        for (int j = 0; j < 8; ++j) acc[i][j] = 0.f;

    for (int kc = 0; kc < 64; kc += 4) {
        uint2 xp0 = *(const uint2*)&xs[kc    ][sg * 4];
        uint2 xp1 = *(const uint2*)&xs[kc + 1][sg * 4];
        uint2 xp2 = *(const uint2*)&xs[kc + 2][sg * 4];
        uint2 xp3 = *(const uint2*)&xs[kc + 3][sg * 4];
        float x0[4] = { bflo(xp0.x), bfhi(xp0.x), bflo(xp0.y), bfhi(xp0.y) };
        float x1[4] = { bflo(xp1.x), bfhi(xp1.x), bflo(xp1.y), bfhi(xp1.y) };
        float x2[4] = { bflo(xp2.x), bfhi(xp2.x), bflo(xp2.y), bfhi(xp2.y) };
        float x3[4] = { bflo(xp3.x), bfhi(xp3.x), bflo(xp3.y), bfhi(xp3.y) };
#pragma unroll
        for (int j = 0; j < 8; ++j) {
            uint2 wp = *(const uint2*)&w1s[og * 8 + j][kc];
            float w0 = bflo(wp.x), w1v = bfhi(wp.x), w2v = bflo(wp.y), w3v = bfhi(wp.y);
#pragma unroll
            for (int i = 0; i < 4; ++i) {
                acc[i][j] = fmaf(x0[i], w0,  acc[i][j]);
                acc[i][j] = fmaf(x1[i], w1v, acc[i][j]);
                acc[i][j] = fmaf(x2[i], w2v, acc[i][j]);
                acc[i][j] = fmaf(x3[i], w3v, acc[i][j]);
            }
        }
    }
#pragma unroll
    for (int j = 0; j < 8; ++j) {
        int o = og * 8 + j;
        float b = b1s[o];
        float h0 = leaky(acc[0][j] + b), h1 = leaky(acc[1][j] + b);
        float h2 = leaky(acc[2][j] + b), h3 = leaky(acc[3][j] + b);
        *(unsigned*)&hs[o][sg * 4]     = (unsigned)f2bf(h0) | ((unsigned)f2bf(h1) << 16);
        *(unsigned*)&hs[o][sg * 4 + 2] = (unsigned)f2bf(h2) | ((unsigned)f2bf(h3) << 16);
    }
    __syncthreads();

    float acc2[4][4];
#pragma unroll
    for (int i = 0; i < 4; ++i)
#pragma unroll
        for (int j = 0; j < 4; ++j) acc2[i][j] = 0.f;

    for (int kc = 0; kc < 128; kc += 4) {
        uint2 hp0 = *(const uint2*)&hs[kc    ][sg * 4];
        uint2 hp1 = *(const uint2*)&hs[kc + 1][sg * 4];
        uint2 hp2 = *(const uint2*)&hs[kc + 2][sg * 4];
        uint2 hp3 = *(const uint2*)&hs[kc + 3][sg * 4];
        float h0[4] = { bflo(hp0.x), bfhi(hp0.x), bflo(hp0.y), bfhi(hp0.y) };
        float h1[4] = { bflo(hp1.x), bfhi(hp1.x), bflo(hp1.y), bfhi(hp1.y) };
        float h2[4] = { bflo(hp2.x), bfhi(hp2.x), bflo(hp2.y), bfhi(hp2.y) };
        float h3[4] = { bflo(hp3.x), bfhi(hp3.x), bflo(hp3.y), bfhi(hp3.y) };
#pragma unroll
        for (int j = 0; j < 4; ++j) {
            uint2 wp = *(const uint2*)&w2s[og * 4 + j][kc];
            float w0 = bflo(wp.x), w1v = bfhi(wp.x), w2v = bflo(wp.y), w3v = bfhi(wp.y);
#pragma unroll
            for (int i = 0; i < 4; ++i) {
                acc2[i][j] = fmaf(h0[i], w0,  acc2[i][j]);
                acc2[i][j] = fmaf(h1[i], w1v, acc2[i][j]);
                acc2[i][j] = fmaf(h2[i], w2v, acc2[i][j]);
                acc2[i][j] = fmaf(h3[i], w3v, acc2[i][j]);
            }
        }
    }
#pragma unroll
    for (int i = 0; i < 4; ++i) {
        float o0 = leaky(acc2[i][0] + b2s[og * 4 + 0]);
        float o1 = leaky(acc2[i][1] + b2s[og * 4 + 1]);
        float o2 = leaky(acc2[i][2] + b2s[og * 4 + 2]);
        float o3 = leaky(acc2[i][3] + b2s[og * 4 + 3]);
        uint2 pp;
        pp.x = (unsigned)f2bf(o0) | ((unsigned)f2bf(o1) << 16);
        pp.y = (unsigned)f2bf(o2) | ((unsigned)f2bf(o3) << 16);
        *(uint2*)(outp + ((size_t)(tile * 64 + sg * 4 + i) * 64 + og * 4)) = pp;
    }
}

// ---------------------------------------------------------------------------
// Pairwise dot + biases + SSE. 4 threads per sample.
// ---------------------------------------------------------------------------
__global__ __launch_bounds__(256) void dot_sse_k(
    const unsigned short* __restrict__ ou, const unsigned short* __restrict__ oi,
    const int* __restrict__ user0, const int* __restrict__ item0,
    const float* __restrict__ ub, const float* __restrict__ ib,
    const float* __restrict__ avg, const float* __restrict__ ratings,
    float* __restrict__ sse)
{
    int g = blockIdx.x * 256 + threadIdx.x;
    int b = g >> 2, q = g & 3;
    const uint4* pu = (const uint4*)(ou + (size_t)b * 64 + q * 16);
    const uint4* pi = (const uint4*)(oi + (size_t)b * 64 + q * 16);
    uint4 a0 = pu[0], a1 = pu[1];
    uint4 c0 = pi[0], c1 = pi[1];
    float s = 0.f;
#define DOTP(ua, uc) { s = fmaf(bflo(ua), bflo(uc), s); s = fmaf(bfhi(ua), bfhi(uc), s); }
    DOTP(a0.x, c0.x) DOTP(a0.y, c0.y) DOTP(a0.z, c0.z) DOTP(a0.w, c0.w)
    DOTP(a1.x, c1.x) DOTP(a1.y, c1.y) DOTP(a1.z, c1.z) DOTP(a1.w, c1.w)
#undef DOTP
    s += __shfl_xor(s, 1);
    s += __shfl_xor(s, 2);
    float contrib = 0.f;
    if (q == 0) {
        float pred = s + ub[user0[b]] + ib[item0[b]] + avg[0];
        float d = pred - ratings[b];
        contrib = d * d;
    }
    for (int off = 32; off; off >>= 1) contrib += __shfl_down(contrib, off);
    __shared__ float wsum[4];
    int lane = threadIdx.x & 63, wv = threadIdx.x >> 6;
    if (lane == 0) wsum[wv] = contrib;
    __syncthreads();
    if (threadIdx.x == 0)
        atomicAdd(sse, wsum[0] + wsum[1] + wsum[2] + wsum[3]);
}

__global__ __launch_bounds__(256) void finalize2_k(
    const float* __restrict__ accU, const float* __restrict__ accI,
    const float* __restrict__ sse, float* __restrict__ out)
{
    int t = threadIdx.x;
    float su = 0.f, si = 0.f;
    for (int i = t; i < ACC_SLOTS; i += 256) { su += accU[i]; si += accI[i]; }
    for (int off = 32; off; off >>= 1) {
        su += __shfl_down(su, off);
        si += __shfl_down(si, off);
    }
    __shared__ float s[8];
    int wv = t >> 6, lane = t & 63;
    if (lane == 0) { s[wv] = su; s[wv + 4] = si; }
    __syncthreads();
    if (t == 0) {
        float SU = s[0] + s[1] + s[2] + s[3];
        float SI = s[4] + s[5] + s[6] + s[7];
        out[0] = sse[0] / (float)BATCH
               + LAM_F * (SU / (float)((double)U_NUM * 64.0))
               + LAM_F * (SI / (float)((double)I_NUM * 64.0));
    }
}

// ---------------------------------------------------------------------------

extern "C" void kernel_launch(void* const* d_in, const int* in_sizes, int n_in,
                              void* d_out, int out_size, void* d_ws, size_t ws_size,
                              hipStream_t stream)
{
    const int*   ui_rows = (const int*)d_in[0];
    const int*   ui_cols = (const int*)d_in[1];
    const float* ui_vals = (const float*)d_in[2];
    const float* iu_vals = (const float*)d_in[3];
    const float* d_i     = (const float*)d_in[4];
    const float* d_j     = (const float*)d_in[5];
    const float* eu      = (const float*)d_in[6];
    const float* ei      = (const float*)d_in[7];
    const float* add_w   = (const float*)d_in[8];
    const float* fw1     = (const float*)d_in[9];
    const float* fb1     = (const float*)d_in[10];
    const float* fw2     = (const float*)d_in[11];
    const float* fb2     = (const float*)d_in[12];
    const float* ub      = (const float*)d_in[13];
    const float* ib      = (const float*)d_in[14];
    const float* avg     = (const float*)d_in[15];
    const int*   user0   = (const int*)d_in[16];
    const int*   item0   = (const int*)d_in[17];
    const float* ratings = (const float*)d_in[18];

    const size_t U64 = (size_t)U_NUM * DDIM;   // 22,998,208
    const size_t I64 = (size_t)I_NUM * DDIM;   // 18,725,696

    // ---- workspace layout (~311 MB; known-safe < 334 MB) ----
    int*            ecol_u = (int*)d_ws;                       // NNZ (16 MB)
    unsigned short* eval_u = (unsigned short*)(ecol_u + NNZ_N);// NNZ (8 MB)
    int*            ecol_i = (int*)(eval_u + NNZ_N);           // NNZ
    unsigned short* eval_i = (unsigned short*)(ecol_i + NNZ_N);// NNZ
    int2* tmpb  = (int2*)(eval_i + NNZ_N);                     // NNZ int2 (32 MB)
    // overlay inside tmpb (dead after l2sort): g1u_f8 (23 MB) + ou/oi (8.4 MB)
    unsigned char*  g1u_f8 = (unsigned char*)tmpb;             // U64 B
    unsigned short* ou_bf  = (unsigned short*)(g1u_f8 + ((U64 + 15) & ~15ull)); // BATCH*64
    unsigned short* oi_bf  = ou_bf + (size_t)BATCH * 64;
    int*  gh    = (int*)(tmpb + NNZ_N);                        // NB_U*NBLK max
    int*  bsum  = gh + (size_t)NB_U * NBLK;                    // 512
    int*  ptr_u = bsum + 512;                                  // U+1
    int*  ptr_i = ptr_u + (U_NUM + 1);                         // I+1
    float* accU = (float*)(ptr_i + (I_NUM + 1));               // ACC_SLOTS
    float* accI = accU + ACC_SLOTS;                            // ACC_SLOTS
    float* sse  = accI + ACC_SLOTS;                            // 4
    unsigned short* eu_bf  = (unsigned short*)(sse + 4);       // U64
    unsigned short* ei_bf  = eu_bf + U64;                      // I64 (becomes gcnI in-place)
    unsigned short* g1u_bf = ei_bf + I64;                      // U64 (becomes gcnU in-place)
    unsigned short* g1i_bf = g1u_bf + U64;                     // I64
    unsigned char*  eu_f8  = (unsigned char*)(g1i_bf + I64);   // U64 B
    unsigned char*  ei_f8  = eu_f8 + U64;                      // I64 B
    unsigned char*  g1i_f8 = ei_f8 + I64;                      // I64 B
    (void)ws_size;

    dim3 blk(256);
    int gu = (U_NUM + 3) / 4, gi = (I_NUM + 3) / 4;

    hipMemsetAsync(accU, 0, (2 * ACC_SLOTS + 4) * sizeof(float), stream);

    f2bf8_k<<<2048, blk, 0, stream>>>((const float4*)eu, (ushort4*)eu_bf,
                                      (uchar4*)eu_f8, U64 / 4);
    f2bf8_k<<<2048, blk, 0, stream>>>((const float4*)ei, (ushort4*)ei_bf,
                                      (uchar4*)ei_f8, I64 / 4);

    // ---- user-side CSR (key = ui_rows) ----
    {
        int n = NB_U * NBLK;
        int nb1 = (n + 1023) / 1024;
        l1hist_k<<<NBLK, blk, 0, stream>>>(ui_rows, gh, NB_U);
        scan1_k<<<nb1, blk, 0, stream>>>(gh, n, bsum);
        scan2_k<<<1, 512, 0, stream>>>(bsum, nb1);
        scan3_k<<<nb1, blk, 0, stream>>>(gh, n, bsum);
        l1scatter_k<<<NBLK, blk, 0, stream>>>(ui_rows, gh, NB_U, tmpb);
        l2sort_k<<<NB_U, blk, 0, stream>>>(tmpb, gh, NB_U, ui_cols, ui_vals,
                                           ptr_u, U_NUM, ecol_u, eval_u);
    }
    // ---- item-side CSR (key = ui_cols) ----
    {
        int n = NB_I * NBLK;
        int nb1 = (n + 1023) / 1024;
        l1hist_k<<<NBLK, blk, 0, stream>>>(ui_cols, gh, NB_I);
        scan1_k<<<nb1, blk, 0, stream>>>(gh, n, bsum);
        scan2_k<<<1, 512, 0, stream>>>(bsum, nb1);
        scan3_k<<<nb1, blk, 0, stream>>>(gh, n, bsum);
        l1scatter_k<<<NBLK, blk, 0, stream>>>(ui_cols, gh, NB_I, tmpb);
        l2sort_k<<<NB_I, blk, 0, stream>>>(tmpb, gh, NB_I, ui_rows, iu_vals,
                                           ptr_i, I_NUM, ecol_i, eval_i);
    }
    // NOTE: tmpb is dead from here; g1u_f8 / ou / oi live in its space.

    // ---- GCN layers (fp8 gathers) ----
    // layer 1
    spmm_csr_k<0><<<gu, blk, 0, stream>>>(ptr_u, ecol_u, eval_u, ei_f8, eu_bf, d_i,
                                          g1u_bf, U_NUM, g1u_f8, nullptr, nullptr, nullptr);
    spmm_csr_k<0><<<gi, blk, 0, stream>>>(ptr_i, ecol_i, eval_i, eu_f8, ei_bf, d_j,
                                          g1i_bf, I_NUM, g1i_f8, nullptr, nullptr, nullptr);
    // layer 2 + combine + fused L2 partials
    // gcn_i in-place over ei_bf (embed aliases out); gathers g1u_f8
    spmm_csr_k<1><<<gi, blk, 0, stream>>>(ptr_i, ecol_i, eval_i, g1u_f8, g1i_bf, d_j,
                                          ei_bf, I_NUM, nullptr, ei_bf, add_w, accI);
    // gcn_u in-place over g1u_bf (base aliases out); gathers g1i_f8
    spmm_csr_k<1><<<gu, blk, 0, stream>>>(ptr_u, ecol_u, eval_u, g1i_f8, g1u_bf, d_i,
                                          g1u_bf, U_NUM, nullptr, eu_bf, add_w, accU);

    // ---- MLP (tiled GEMM) + dot/SSE ----
    mlp_k<<<1024, blk, 0, stream>>>(user0, item0, g1u_bf, ei_bf,
                                    fw1, fb1, fw2, fb2, ou_bf, oi_bf);
    dot_sse_k<<<BATCH * 4 / 256, blk, 0, stream>>>(ou_bf, oi_bf, user0, item0,
                                                   ub, ib, avg, ratings, sse);
    finalize2_k<<<1, blk, 0, stream>>>(accU, accI, sse, (float*)d_out);
}

// Round 9
// 1323.104 us; speedup vs baseline: 1.0052x; 1.0052x over previous
//
#include <hip/hip_runtime.h>

#define U_NUM 359347
#define I_NUM 292589
#define DDIM  64
#define NNZ_N 4000000
#define BATCH 32768
#define LAM_F 0.001f
#define ACC_SLOTS 2048

#define EPB   4096                          // edges per level-1 block
#define NBLK  ((NNZ_N + EPB - 1) / EPB)     // 977
#define NB_U  ((U_NUM + 1023) >> 10)        // 351
#define NB_I  ((I_NUM + 1023) >> 10)        // 286

__device__ __forceinline__ float leaky(float x) { return x > 0.f ? x : 0.1f * x; }

__device__ __forceinline__ unsigned short f2bf(float f) {
    unsigned b = __float_as_uint(f);
    b = (b + 0x7FFF + ((b >> 16) & 1)) >> 16;   // RNE
    return (unsigned short)b;
}
__device__ __forceinline__ float bf2f(unsigned short u) {
    return __uint_as_float((unsigned)u << 16);
}
__device__ __forceinline__ float bflo(unsigned u) { return __uint_as_float(u << 16); }
__device__ __forceinline__ float bfhi(unsigned u) { return __uint_as_float(u & 0xffff0000u); }

// ---- fp8 e4m3fn (OCP, bias 7) with global scale 64 folded at encode ----
__device__ __forceinline__ unsigned char f2fp8(float v) {
    v = fminf(fmaxf(v * 64.f, -440.f), 440.f);
    unsigned b = __float_as_uint(v * 0x1p-120f);
    unsigned sign = (b >> 24) & 0x80u;
    unsigned mag = b & 0x7fffffffu;
    mag += 0x7ffffu + ((mag >> 20) & 1u);        // RNE to 3 mantissa bits
    return (unsigned char)(sign | ((mag >> 20) & 0x7fu));
}

// decode WITHOUT the 1/64 (scale folded into edge values instead):
// returns 64 * true_value
#if __has_builtin(__builtin_amdgcn_cvt_f32_fp8)
#define FP8DEC(b) __builtin_amdgcn_cvt_f32_fp8((int)(b), 0)
#else
#define FP8DEC(b) (__uint_as_float(((unsigned)((b) & 0x80u) << 24) | \
                                   ((unsigned)((b) & 0x7fu) << 20)) * 0x1p120f)
#endif

// ---------------------------------------------------------------------------
// fp32 -> bf16 + fp8 bulk convert
// ---------------------------------------------------------------------------
__global__ __launch_bounds__(256) void f2bf8_k(
    const float4* __restrict__ in, ushort4* __restrict__ outb,
    uchar4* __restrict__ out8, size_t n4)
{
    size_t stride = (size_t)gridDim.x * 256;
    for (size_t i = (size_t)blockIdx.x * 256 + threadIdx.x; i < n4; i += stride) {
        float4 v = in[i];
        ushort4 o;
        o.x = f2bf(v.x); o.y = f2bf(v.y); o.z = f2bf(v.z); o.w = f2bf(v.w);
        outb[i] = o;
        uchar4 p;
        p.x = f2fp8(v.x); p.y = f2fp8(v.y); p.z = f2fp8(v.z); p.w = f2fp8(v.w);
        out8[i] = p;
    }
}

// ---------------------------------------------------------------------------
// Level-1: bucket histogram per block  (bucket = key >> 10)
// ---------------------------------------------------------------------------
__global__ __launch_bounds__(256) void l1hist_k(
    const int* __restrict__ keys, int* __restrict__ gh, int nb)
{
    __shared__ int h[512];
    for (int i = threadIdx.x; i < nb; i += 256) h[i] = 0;
    __syncthreads();
    int base = blockIdx.x * EPB;
    int end = min(base + EPB, NNZ_N);
    for (int e = base + threadIdx.x; e < end; e += 256)
        atomicAdd(&h[keys[e] >> 10], 1);
    __syncthreads();
    for (int i = threadIdx.x; i < nb; i += 256)
        gh[i * NBLK + blockIdx.x] = h[i];
}

__global__ __launch_bounds__(256) void scan1_k(int* __restrict__ a, int n, int* __restrict__ bsum)
{
    __shared__ int s[256];
    int t = threadIdx.x;
    int base = blockIdx.x * 1024 + t * 4;
    int v[4];
#pragma unroll
    for (int j = 0; j < 4; ++j) v[j] = (base + j < n) ? a[base + j] : 0;
    s[t] = v[0] + v[1] + v[2] + v[3];
    __syncthreads();
    for (int off = 1; off < 256; off <<= 1) {
        int x = (t >= off) ? s[t - off] : 0;
        __syncthreads();
        s[t] += x;
        __syncthreads();
    }
    if (t == 255) bsum[blockIdx.x] = s[255];
    int run = (t > 0) ? s[t - 1] : 0;
#pragma unroll
    for (int j = 0; j < 4; ++j) {
        if (base + j < n) a[base + j] = run;
        run += v[j];
    }
}

__global__ __launch_bounds__(512) void scan2_k(int* __restrict__ bsum, int nb)
{
    __shared__ int s[512];
    int t = threadIdx.x;
    int v = (t < nb) ? bsum[t] : 0;
    s[t] = v;
    __syncthreads();
    for (int off = 1; off < 512; off <<= 1) {
        int x = (t >= off) ? s[t - off] : 0;
        __syncthreads();
        s[t] += x;
        __syncthreads();
    }
    if (t < nb) bsum[t] = s[t] - v;   // exclusive
}

__global__ __launch_bounds__(256) void scan3_k(int* __restrict__ a, int n,
                                               const int* __restrict__ bsum)
{
    int add = bsum[blockIdx.x];
    int base = blockIdx.x * 1024 + threadIdx.x * 4;
#pragma unroll
    for (int j = 0; j < 4; ++j)
        if (base + j < n) a[base + j] += add;
}

__global__ __launch_bounds__(256) void l1scatter_k(
    const int* __restrict__ keys, const int* __restrict__ gh, int nb,
    int2* __restrict__ out)
{
    __shared__ int cur[512];
    for (int i = threadIdx.x; i < nb; i += 256) cur[i] = gh[i * NBLK + blockIdx.x];
    __syncthreads();
    int base = blockIdx.x * EPB;
    int end = min(base + EPB, NNZ_N);
    for (int e = base + threadIdx.x; e < end; e += 256) {
        int k = keys[e];
        int pos = atomicAdd(&cur[k >> 10], 1);
        out[pos] = make_int2(k, e);
    }
}

// Level-2: LDS counting sort per bucket; emits ptr and split (col, bf16 val).
// Edge values pre-scaled by 1/64 (fp8 dequant folded here).
__global__ __launch_bounds__(256) void l2sort_k(
    const int2* __restrict__ tmp, const int* __restrict__ gh, int nb,
    const int* __restrict__ colArr, const float* __restrict__ valArr,
    int* __restrict__ ptr, int nrows,
    int* __restrict__ ecol, unsigned short* __restrict__ eval)
{
    __shared__ int hist[1024];
    __shared__ int ssc[256];
    int b = blockIdx.x;
    int t = threadIdx.x;
    int bucket_base = gh[b * NBLK];
    int bucket_end  = (b == nb - 1) ? NNZ_N : gh[(b + 1) * NBLK];
    for (int i = t; i < 1024; i += 256) hist[i] = 0;
    __syncthreads();
    for (int e = bucket_base + t; e < bucket_end; e += 256)
        atomicAdd(&hist[tmp[e].x & 1023], 1);
    __syncthreads();
    int v0 = hist[t * 4], v1 = hist[t * 4 + 1], v2 = hist[t * 4 + 2], v3 = hist[t * 4 + 3];
    ssc[t] = v0 + v1 + v2 + v3;
    __syncthreads();
    for (int off = 1; off < 256; off <<= 1) {
        int x = (t >= off) ? ssc[t - off] : 0;
        __syncthreads();
        ssc[t] += x;
        __syncthreads();
    }
    int run = (t > 0) ? ssc[t - 1] : 0;
    int g0 = run, g1 = run + v0, g2 = g1 + v1, g3 = g2 + v2;
    hist[t * 4] = g0; hist[t * 4 + 1] = g1; hist[t * 4 + 2] = g2; hist[t * 4 + 3] = g3;
    int rbase = b << 10;
    if (rbase + t * 4 < nrows)     ptr[rbase + t * 4]     = bucket_base + g0;
    if (rbase + t * 4 + 1 < nrows) ptr[rbase + t * 4 + 1] = bucket_base + g1;
    if (rbase + t * 4 + 2 < nrows) ptr[rbase + t * 4 + 2] = bucket_base + g2;
    if (rbase + t * 4 + 3 < nrows) ptr[rbase + t * 4 + 3] = bucket_base + g3;
    if (b == nb - 1 && t == 0) ptr[nrows] = NNZ_N;
    __syncthreads();
    for (int e = bucket_base + t; e < bucket_end; e += 256) {
        int2 q = tmp[e];
        int pos = bucket_base + atomicAdd(&hist[q.x & 1023], 1);
        ecol[pos] = colArr[q.y];
        eval[pos] = f2bf(valArr[q.y] * 0.015625f);   // val / 64
    }
}

// ---------------------------------------------------------------------------
// CSR SpMM: gathers fp8 rows (64 B/edge) decoded by HW cvt, streams bf16.
// MODE 0: o = relu(A@x + base*deg); write bf16 + fp8 copies.
// MODE 1: o = relu(A@x + base*deg); out = w0*embed + w1*base + w2*o (bf16);
//         accumulate sum(out^2).  base/out and embed/out may alias.
// ---------------------------------------------------------------------------
template <int MODE>
__global__ __launch_bounds__(256) void spmm_csr_k(
    const int* __restrict__ ptr, const int* __restrict__ ecol,
    const unsigned short* __restrict__ eval,
    const unsigned char* __restrict__ x8, const unsigned short* base,
    const float* __restrict__ deg, unsigned short* out, int nrows,
    unsigned char* __restrict__ out8,
    const unsigned short* embed, const float* __restrict__ add_w,
    float* __restrict__ accArr)
{
    int wv = threadIdx.x >> 6, lane = threadIdx.x & 63;
    int r = blockIdx.x * 4 + wv;
    __shared__ float ssum[4];
    if (r < nrows) {
        int s0 = __builtin_amdgcn_readfirstlane(ptr[r]);
        int e0 = __builtin_amdgcn_readfirstlane(ptr[r + 1]);
        float a0 = 0.f, a1 = 0.f, a2 = 0.f, a3 = 0.f;
        int k = s0;
        for (; k + 4 <= e0; k += 4) {
            int c0 = ecol[k], c1 = ecol[k + 1], c2 = ecol[k + 2], c3 = ecol[k + 3];
            float v0 = bf2f(eval[k]),     v1 = bf2f(eval[k + 1]);
            float v2 = bf2f(eval[k + 2]), v3 = bf2f(eval[k + 3]);
            unsigned char b0 = x8[(size_t)c0 * DDIM + lane];
            unsigned char b1 = x8[(size_t)c1 * DDIM + lane];
            unsigned char b2 = x8[(size_t)c2 * DDIM + lane];
            unsigned char b3 = x8[(size_t)c3 * DDIM + lane];
            a0 = fmaf(v0, FP8DEC(b0), a0);
            a1 = fmaf(v1, FP8DEC(b1), a1);
            a2 = fmaf(v2, FP8DEC(b2), a2);
            a3 = fmaf(v3, FP8DEC(b3), a3);
        }
        for (; k < e0; ++k)
            a0 = fmaf(bf2f(eval[k]), FP8DEC(x8[(size_t)ecol[k] * DDIM + lane]), a0);
        float acc = (a0 + a1) + (a2 + a3);
        float bb = bf2f(base[(size_t)r * DDIM + lane]);
        float o = fmaxf(fmaf(bb, deg[r], acc), 0.f);
        if (MODE == 0) {
            out[(size_t)r * DDIM + lane] = f2bf(o);
            out8[(size_t)r * DDIM + lane] = f2fp8(o);
        } else {
            float g = fmaf(add_w[0], bf2f(embed[(size_t)r * DDIM + lane]),
                           fmaf(add_w[1], bb, add_w[2] * o));
            out[(size_t)r * DDIM + lane] = f2bf(g);
            float sq = g * g;
            for (int off = 32; off; off >>= 1) sq += __shfl_down(sq, off);
            if (lane == 0) ssum[wv] = sq;
        }
    } else if (MODE == 1) {
        if (lane == 0) ssum[wv] = 0.f;
    }
    if (MODE == 1) {
        __syncthreads();
        if (threadIdx.x == 0)
            atomicAdd(&accArr[blockIdx.x & (ACC_SLOTS - 1)],
                      ssum[0] + ssum[1] + ssum[2] + ssum[3]);
    }
}

// ---------------------------------------------------------------------------
// MLP as block-tiled VALU GEMM (unchanged)
// ---------------------------------------------------------------------------
__global__ __launch_bounds__(256) void mlp_k(
    const int* __restrict__ user0, const int* __restrict__ item0,
    const unsigned short* __restrict__ gcnU, const unsigned short* __restrict__ gcnI,
    const float* __restrict__ fw1, const float* __restrict__ fb1,
    const float* __restrict__ fw2, const float* __restrict__ fb2,
    unsigned short* __restrict__ ou, unsigned short* __restrict__ oi)
{
    __shared__ unsigned short xs[64][72];
    __shared__ unsigned short w1s[128][68];
    __shared__ unsigned short w2s[64][140];
    __shared__ unsigned short hs[128][72];
    __shared__ float b1s[128];
    __shared__ float b2s[64];

    int t = threadIdx.x;
    int side = blockIdx.x >> 9;
    int tile = blockIdx.x & 511;
    const int* sel = side ? item0 : user0;
    const unsigned short* gcn = side ? gcnI : gcnU;
    unsigned short* outp = side ? oi : ou;

    {
        int r = t >> 2, c = t & 3;
        int idx = sel[tile * 64 + r];
        const ushort4* src = (const ushort4*)(gcn + (size_t)idx * 64 + c * 16);
        ushort4 v0 = src[0], v1 = src[1], v2 = src[2], v3 = src[3];
        int k0 = c * 16;
        xs[k0 +  0][r] = v0.x; xs[k0 +  1][r] = v0.y; xs[k0 +  2][r] = v0.z; xs[k0 +  3][r] = v0.w;
        xs[k0 +  4][r] = v1.x; xs[k0 +  5][r] = v1.y; xs[k0 +  6][r] = v1.z; xs[k0 +  7][r] = v1.w;
        xs[k0 +  8][r] = v2.x; xs[k0 +  9][r] = v2.y; xs[k0 + 10][r] = v2.z; xs[k0 + 11][r] = v2.w;
        xs[k0 + 12][r] = v3.x; xs[k0 + 13][r] = v3.y; xs[k0 + 14][r] = v3.z; xs[k0 + 15][r] = v3.w;
    }
#pragma unroll
    for (int i = 0; i < 8; ++i) {
        int flat = i * 1024 + t * 4;
        float4 w = *(const float4*)(fw1 + flat);
        int o = flat >> 6, k = flat & 63;
        *(unsigned*)&w1s[o][k]     = (unsigned)f2bf(w.x) | ((unsigned)f2bf(w.y) << 16);
        *(unsigned*)&w1s[o][k + 2] = (unsigned)f2bf(w.z) | ((unsigned)f2bf(w.w) << 16);
        float4 u = *(const float4*)(fw2 + flat);
        int o2 = flat >> 7, k2 = flat & 127;
        *(unsigned*)&w2s[o2][k2]     = (unsigned)f2bf(u.x) | ((unsigned)f2bf(u.y) << 16);
        *(unsigned*)&w2s[o2][k2 + 2] = (unsigned)f2bf(u.z) | ((unsigned)f2bf(u.w) << 16);
    }
    if (t < 128) b1s[t] = fb1[t];
    if (t < 64)  b2s[t] = fb2[t];
    __syncthreads();

    int sg = t & 15, og = t >> 4;

    float acc[4][8];
#pragma unroll
    for (int i = 0; i < 4; ++i)
#pragma unroll
        for (int j = 0; j < 8; ++j) acc[i][j] = 0.f;

    for (int kc = 0; kc < 64; kc += 4) {
        uint2 xp0 = *(const uint2*)&xs[kc    ][sg * 4];
        uint2 xp1 = *(const uint2*)&xs[kc + 1][sg * 4];
        uint2 xp2 = *(const uint2*)&xs[kc + 2][sg * 4];
        uint2 xp3 = *(const uint2*)&xs[kc + 3][sg * 4];
        float x0[4] = { bflo(xp0.x), bfhi(xp0.x), bflo(xp0.y), bfhi(xp0.y) };
        float x1[4] = { bflo(xp1.x), bfhi(xp1.x), bflo(xp1.y), bfhi(xp1.y) };
        float x2[4] = { bflo(xp2.x), bfhi(xp2.x), bflo(xp2.y), bfhi(xp2.y) };
        float x3[4] = { bflo(xp3.x), bfhi(xp3.x), bflo(xp3.y), bfhi(xp3.y) };
#pragma unroll
        for (int j = 0; j < 8; ++j) {
            uint2 wp = *(const uint2*)&w1s[og * 8 + j][kc];
            float w0 = bflo(wp.x), w1v = bfhi(wp.x), w2v = bflo(wp.y), w3v = bfhi(wp.y);
#pragma unroll
            for (int i = 0; i < 4; ++i) {
                acc[i][j] = fmaf(x0[i], w0,  acc[i][j]);
                acc[i][j] = fmaf(x1[i], w1v, acc[i][j]);
                acc[i][j] = fmaf(x2[i], w2v, acc[i][j]);
                acc[i][j] = fmaf(x3[i], w3v, acc[i][j]);
            }
        }
    }
#pragma unroll
    for (int j = 0; j < 8; ++j) {
        int o = og * 8 + j;
        float b = b1s[o];
        float h0 = leaky(acc[0][j] + b), h1 = leaky(acc[1][j] + b);
        float h2 = leaky(acc[2][j] + b), h3 = leaky(acc[3][j] + b);
        *(unsigned*)&hs[o][sg * 4]     = (unsigned)f2bf(h0) | ((unsigned)f2bf(h1) << 16);
        *(unsigned*)&hs[o][sg * 4 + 2] = (unsigned)f2bf(h2) | ((unsigned)f2bf(h3) << 16);
    }
    __syncthreads();

    float acc2[4][4];
#pragma unroll
    for (int i = 0; i < 4; ++i)
#pragma unroll
        for (int j = 0; j < 4; ++j) acc2[i][j] = 0.f;

    for (int kc = 0; kc < 128; kc += 4) {
        uint2 hp0 = *(const uint2*)&hs[kc    ][sg * 4];
        uint2 hp1 = *(const uint2*)&hs[kc + 1][sg * 4];
        uint2 hp2 = *(const uint2*)&hs[kc + 2][sg * 4];
        uint2 hp3 = *(const uint2*)&hs[kc + 3][sg * 4];
        float h0[4] = { bflo(hp0.x), bfhi(hp0.x), bflo(hp0.y), bfhi(hp0.y) };
        float h1[4] = { bflo(hp1.x), bfhi(hp1.x), bflo(hp1.y), bfhi(hp1.y) };
        float h2[4] = { bflo(hp2.x), bfhi(hp2.x), bflo(hp2.y), bfhi(hp2.y) };
        float h3[4] = { bflo(hp3.x), bfhi(hp3.x), bflo(hp3.y), bfhi(hp3.y) };
#pragma unroll
        for (int j = 0; j < 4; ++j) {
            uint2 wp = *(const uint2*)&w2s[og * 4 + j][kc];
            float w0 = bflo(wp.x), w1v = bfhi(wp.x), w2v = bflo(wp.y), w3v = bfhi(wp.y);
#pragma unroll
            for (int i = 0; i < 4; ++i) {
                acc2[i][j] = fmaf(h0[i], w0,  acc2[i][j]);
                acc2[i][j] = fmaf(h1[i], w1v, acc2[i][j]);
                acc2[i][j] = fmaf(h2[i], w2v, acc2[i][j]);
                acc2[i][j] = fmaf(h3[i], w3v, acc2[i][j]);
            }
        }
    }
#pragma unroll
    for (int i = 0; i < 4; ++i) {
        float o0 = leaky(acc2[i][0] + b2s[og * 4 + 0]);
        float o1 = leaky(acc2[i][1] + b2s[og * 4 + 1]);
        float o2 = leaky(acc2[i][2] + b2s[og * 4 + 2]);
        float o3 = leaky(acc2[i][3] + b2s[og * 4 + 3]);
        uint2 pp;
        pp.x = (unsigned)f2bf(o0) | ((unsigned)f2bf(o1) << 16);
        pp.y = (unsigned)f2bf(o2) | ((unsigned)f2bf(o3) << 16);
        *(uint2*)(outp + ((size_t)(tile * 64 + sg * 4 + i) * 64 + og * 4)) = pp;
    }
}

// ---------------------------------------------------------------------------
// Pairwise dot + biases + SSE. 4 threads per sample.
// ---------------------------------------------------------------------------
__global__ __launch_bounds__(256) void dot_sse_k(
    const unsigned short* __restrict__ ou, const unsigned short* __restrict__ oi,
    const int* __restrict__ user0, const int* __restrict__ item0,
    const float* __restrict__ ub, const float* __restrict__ ib,
    const float* __restrict__ avg, const float* __restrict__ ratings,
    float* __restrict__ sse)
{
    int g = blockIdx.x * 256 + threadIdx.x;
    int b = g >> 2, q = g & 3;
    const uint4* pu = (const uint4*)(ou + (size_t)b * 64 + q * 16);
    const uint4* pi = (const uint4*)(oi + (size_t)b * 64 + q * 16);
    uint4 a0 = pu[0], a1 = pu[1];
    uint4 c0 = pi[0], c1 = pi[1];
    float s = 0.f;
#define DOTP(ua, uc) { s = fmaf(bflo(ua), bflo(uc), s); s = fmaf(bfhi(ua), bfhi(uc), s); }
    DOTP(a0.x, c0.x) DOTP(a0.y, c0.y) DOTP(a0.z, c0.z) DOTP(a0.w, c0.w)
    DOTP(a1.x, c1.x) DOTP(a1.y, c1.y) DOTP(a1.z, c1.z) DOTP(a1.w, c1.w)
#undef DOTP
    s += __shfl_xor(s, 1);
    s += __shfl_xor(s, 2);
    float contrib = 0.f;
    if (q == 0) {
        float pred = s + ub[user0[b]] + ib[item0[b]] + avg[0];
        float d = pred - ratings[b];
        contrib = d * d;
    }
    for (int off = 32; off; off >>= 1) contrib += __shfl_down(contrib, off);
    __shared__ float wsum[4];
    int lane = threadIdx.x & 63, wv = threadIdx.x >> 6;
    if (lane == 0) wsum[wv] = contrib;
    __syncthreads();
    if (threadIdx.x == 0)
        atomicAdd(sse, wsum[0] + wsum[1] + wsum[2] + wsum[3]);
}

__global__ __launch_bounds__(256) void finalize2_k(
    const float* __restrict__ accU, const float* __restrict__ accI,
    const float* __restrict__ sse, float* __restrict__ out)
{
    int t = threadIdx.x;
    float su = 0.f, si = 0.f;
    for (int i = t; i < ACC_SLOTS; i += 256) { su += accU[i]; si += accI[i]; }
    for (int off = 32; off; off >>= 1) {
        su += __shfl_down(su, off);
        si += __shfl_down(si, off);
    }
    __shared__ float s[8];
    int wv = t >> 6, lane = t & 63;
    if (lane == 0) { s[wv] = su; s[wv + 4] = si; }
    __syncthreads();
    if (t == 0) {
        float SU = s[0] + s[1] + s[2] + s[3];
        float SI = s[4] + s[5] + s[6] + s[7];
        out[0] = sse[0] / (float)BATCH
               + LAM_F * (SU / (float)((double)U_NUM * 64.0))
               + LAM_F * (SI / (float)((double)I_NUM * 64.0));
    }
}

// ---------------------------------------------------------------------------

extern "C" void kernel_launch(void* const* d_in, const int* in_sizes, int n_in,
                              void* d_out, int out_size, void* d_ws, size_t ws_size,
                              hipStream_t stream)
{
    const int*   ui_rows = (const int*)d_in[0];
    const int*   ui_cols = (const int*)d_in[1];
    const float* ui_vals = (const float*)d_in[2];
    const float* iu_vals = (const float*)d_in[3];
    const float* d_i     = (const float*)d_in[4];
    const float* d_j     = (const float*)d_in[5];
    const float* eu      = (const float*)d_in[6];
    const float* ei      = (const float*)d_in[7];
    const float* add_w   = (const float*)d_in[8];
    const float* fw1     = (const float*)d_in[9];
    const float* fb1     = (const float*)d_in[10];
    const float* fw2     = (const float*)d_in[11];
    const float* fb2     = (const float*)d_in[12];
    const float* ub      = (const float*)d_in[13];
    const float* ib      = (const float*)d_in[14];
    const float* avg     = (const float*)d_in[15];
    const int*   user0   = (const int*)d_in[16];
    const int*   item0   = (const int*)d_in[17];
    const float* ratings = (const float*)d_in[18];

    const size_t U64 = (size_t)U_NUM * DDIM;   // 22,998,208
    const size_t I64 = (size_t)I_NUM * DDIM;   // 18,725,696

    // ---- workspace layout (~311 MB; known-safe < 334 MB) ----
    int*            ecol_u = (int*)d_ws;                       // NNZ (16 MB)
    unsigned short* eval_u = (unsigned short*)(ecol_u + NNZ_N);// NNZ (8 MB)
    int*            ecol_i = (int*)(eval_u + NNZ_N);           // NNZ
    unsigned short* eval_i = (unsigned short*)(ecol_i + NNZ_N);// NNZ
    int2* tmpb  = (int2*)(eval_i + NNZ_N);                     // NNZ int2 (32 MB)
    // overlay inside tmpb (dead after l2sort): g1u_f8 (23 MB) + ou/oi (8.4 MB)
    unsigned char*  g1u_f8 = (unsigned char*)tmpb;             // U64 B
    unsigned short* ou_bf  = (unsigned short*)(g1u_f8 + ((U64 + 15) & ~15ull)); // BATCH*64
    unsigned short* oi_bf  = ou_bf + (size_t)BATCH * 64;
    int*  gh    = (int*)(tmpb + NNZ_N);                        // NB_U*NBLK max
    int*  bsum  = gh + (size_t)NB_U * NBLK;                    // 512
    int*  ptr_u = bsum + 512;                                  // U+1
    int*  ptr_i = ptr_u + (U_NUM + 1);                         // I+1
    float* accU = (float*)(ptr_i + (I_NUM + 1));               // ACC_SLOTS
    float* accI = accU + ACC_SLOTS;                            // ACC_SLOTS
    float* sse  = accI + ACC_SLOTS;                            // 4
    unsigned short* eu_bf  = (unsigned short*)(sse + 4);       // U64
    unsigned short* ei_bf  = eu_bf + U64;                      // I64 (becomes gcnI in-place)
    unsigned short* g1u_bf = ei_bf + I64;                      // U64 (becomes gcnU in-place)
    unsigned short* g1i_bf = g1u_bf + U64;                     // I64
    unsigned char*  eu_f8  = (unsigned char*)(g1i_bf + I64);   // U64 B
    unsigned char*  ei_f8  = eu_f8 + U64;                      // I64 B
    unsigned char*  g1i_f8 = ei_f8 + I64;                      // I64 B
    (void)ws_size;

    dim3 blk(256);
    int gu = (U_NUM + 3) / 4, gi = (I_NUM + 3) / 4;

    hipMemsetAsync(accU, 0, (2 * ACC_SLOTS + 4) * sizeof(float), stream);

    f2bf8_k<<<2048, blk, 0, stream>>>((const float4*)eu, (ushort4*)eu_bf,
                                      (uchar4*)eu_f8, U64 / 4);
    f2bf8_k<<<2048, blk, 0, stream>>>((const float4*)ei, (ushort4*)ei_bf,
                                      (uchar4*)ei_f8, I64 / 4);

    // ---- user-side CSR (key = ui_rows) ----
    {
        int n = NB_U * NBLK;
        int nb1 = (n + 1023) / 1024;
        l1hist_k<<<NBLK, blk, 0, stream>>>(ui_rows, gh, NB_U);
        scan1_k<<<nb1, blk, 0, stream>>>(gh, n, bsum);
        scan2_k<<<1, 512, 0, stream>>>(bsum, nb1);
        scan3_k<<<nb1, blk, 0, stream>>>(gh, n, bsum);
        l1scatter_k<<<NBLK, blk, 0, stream>>>(ui_rows, gh, NB_U, tmpb);
        l2sort_k<<<NB_U, blk, 0, stream>>>(tmpb, gh, NB_U, ui_cols, ui_vals,
                                           ptr_u, U_NUM, ecol_u, eval_u);
    }
    // ---- item-side CSR (key = ui_cols) ----
    {
        int n = NB_I * NBLK;
        int nb1 = (n + 1023) / 1024;
        l1hist_k<<<NBLK, blk, 0, stream>>>(ui_cols, gh, NB_I);
        scan1_k<<<nb1, blk, 0, stream>>>(gh, n, bsum);
        scan2_k<<<1, 512, 0, stream>>>(bsum, nb1);
        scan3_k<<<nb1, blk, 0, stream>>>(gh, n, bsum);
        l1scatter_k<<<NBLK, blk, 0, stream>>>(ui_cols, gh, NB_I, tmpb);
        l2sort_k<<<NB_I, blk, 0, stream>>>(tmpb, gh, NB_I, ui_rows, iu_vals,
                                           ptr_i, I_NUM, ecol_i, eval_i);
    }
    // NOTE: tmpb is dead from here; g1u_f8 / ou / oi live in its space.

    // ---- GCN layers (fp8 gathers, HW cvt decode) ----
    spmm_csr_k<0><<<gu, blk, 0, stream>>>(ptr_u, ecol_u, eval_u, ei_f8, eu_bf, d_i,
                                          g1u_bf, U_NUM, g1u_f8, nullptr, nullptr, nullptr);
    spmm_csr_k<0><<<gi, blk, 0, stream>>>(ptr_i, ecol_i, eval_i, eu_f8, ei_bf, d_j,
                                          g1i_bf, I_NUM, g1i_f8, nullptr, nullptr, nullptr);
    spmm_csr_k<1><<<gi, blk, 0, stream>>>(ptr_i, ecol_i, eval_i, g1u_f8, g1i_bf, d_j,
                                          ei_bf, I_NUM, nullptr, ei_bf, add_w, accI);
    spmm_csr_k<1><<<gu, blk, 0, stream>>>(ptr_u, ecol_u, eval_u, g1i_f8, g1u_bf, d_i,
                                          g1u_bf, U_NUM, nullptr, eu_bf, add_w, accU);

    // ---- MLP (tiled GEMM) + dot/SSE ----
    mlp_k<<<1024, blk, 0, stream>>>(user0, item0, g1u_bf, ei_bf,
                                    fw1, fb1, fw2, fb2, ou_bf, oi_bf);
    dot_sse_k<<<BATCH * 4 / 256, blk, 0, stream>>>(ou_bf, oi_bf, user0, item0,
                                                   ub, ib, avg, ratings, sse);
    finalize2_k<<<1, blk, 0, stream>>>(accU, accI, sse, (float*)d_out);
}

// Round 10
// 1227.817 us; speedup vs baseline: 1.0832x; 1.0776x over previous
//
#include <hip/hip_runtime.h>

#define U_NUM 359347
#define I_NUM 292589
#define DDIM  64
#define NNZ_N 4000000
#define BATCH 32768
#define LAM_F 0.001f
#define ACC_SLOTS 2048

#define EPB   4096
#define NBLK  ((NNZ_N + EPB - 1) / EPB)     // 977
#define NB_U  ((U_NUM + 1023) >> 10)        // 351
#define NB_I  ((I_NUM + 1023) >> 10)        // 286

__device__ __forceinline__ float leaky(float x) { return x > 0.f ? x : 0.1f * x; }

__device__ __forceinline__ unsigned short f2bf(float f) {
    unsigned b = __float_as_uint(f);
    b = (b + 0x7FFF + ((b >> 16) & 1)) >> 16;   // RNE
    return (unsigned short)b;
}
__device__ __forceinline__ float bf2f(unsigned short u) {
    return __uint_as_float((unsigned)u << 16);
}
__device__ __forceinline__ float bflo(unsigned u) { return __uint_as_float(u << 16); }
__device__ __forceinline__ float bfhi(unsigned u) { return __uint_as_float(u & 0xffff0000u); }

// ---- fp8 e4m3fn (OCP, bias 7), global scale 64 folded at encode ----
__device__ __forceinline__ unsigned char f2fp8(float v) {
    v = fminf(fmaxf(v * 64.f, -440.f), 440.f);
    unsigned b = __float_as_uint(v * 0x1p-120f);
    unsigned sign = (b >> 24) & 0x80u;
    unsigned mag = b & 0x7fffffffu;
    mag += 0x7ffffu + ((mag >> 20) & 1u);
    return (unsigned char)(sign | ((mag >> 20) & 0x7fu));
}
#if __has_builtin(__builtin_amdgcn_cvt_f32_fp8)
#define FP8DEC(b) __builtin_amdgcn_cvt_f32_fp8((int)(b), 0)
#else
#define FP8DEC(b) (__uint_as_float(((unsigned)((b) & 0x80u) << 24) | \
                                   ((unsigned)((b) & 0x7fu) << 20)) * 0x1p120f)
#endif

// ---------------------------------------------------------------------------
// fp32 -> bf16 + fp8, both embeddings in one launch
// ---------------------------------------------------------------------------
__global__ __launch_bounds__(256) void f2bf8_k(
    const float4* __restrict__ inU, ushort4* __restrict__ obU, uchar4* __restrict__ o8U,
    const float4* __restrict__ inI, ushort4* __restrict__ obI, uchar4* __restrict__ o8I,
    size_t nU4, size_t total4)
{
    size_t stride = (size_t)gridDim.x * 256;
    for (size_t i = (size_t)blockIdx.x * 256 + threadIdx.x; i < total4; i += stride) {
        const float4* in; ushort4* ob; uchar4* o8; size_t j;
        if (i < nU4) { in = inU; ob = obU; o8 = o8U; j = i; }
        else         { in = inI; ob = obI; o8 = o8I; j = i - nU4; }
        float4 v = in[j];
        ushort4 o;
        o.x = f2bf(v.x); o.y = f2bf(v.y); o.z = f2bf(v.z); o.w = f2bf(v.w);
        ob[j] = o;
        uchar4 p;
        p.x = f2fp8(v.x); p.y = f2fp8(v.y); p.z = f2fp8(v.z); p.w = f2fp8(v.w);
        o8[j] = p;
    }
}

// ---------------------------------------------------------------------------
// hist for both sides in one launch (bucket = key >> 10)
// ---------------------------------------------------------------------------
__global__ __launch_bounds__(256) void hist2_k(
    const int* __restrict__ rows, const int* __restrict__ cols,
    int* __restrict__ gh_u, int* __restrict__ gh_i)
{
    __shared__ int h[512];
    int sideB = blockIdx.x >= NBLK;
    int blk = sideB ? blockIdx.x - NBLK : blockIdx.x;
    const int* keys = sideB ? cols : rows;
    int nb = sideB ? NB_I : NB_U;
    int* gh = sideB ? gh_i : gh_u;
    for (int i = threadIdx.x; i < nb; i += 256) h[i] = 0;
    __syncthreads();
    int base = blk * EPB;
    int end = min(base + EPB, NNZ_N);
    for (int e = base + threadIdx.x; e < end; e += 256)
        atomicAdd(&h[keys[e] >> 10], 1);
    __syncthreads();
    for (int i = threadIdx.x; i < nb; i += 256)
        gh[i * NBLK + blk] = h[i];
}

// ---------------------------------------------------------------------------
// merged scans (both sides)
// ---------------------------------------------------------------------------
__global__ __launch_bounds__(256) void scan1m_k(
    int* __restrict__ aU, int nUe, int* __restrict__ bsU, int nb1U,
    int* __restrict__ aI, int nIe, int* __restrict__ bsI)
{
    __shared__ int s[256];
    int sideB = (int)blockIdx.x >= nb1U;
    int blk = sideB ? blockIdx.x - nb1U : blockIdx.x;
    int* a = sideB ? aI : aU;
    int n = sideB ? nIe : nUe;
    int* bsum = sideB ? bsI : bsU;
    int t = threadIdx.x;
    int base = blk * 1024 + t * 4;
    int v[4];
#pragma unroll
    for (int j = 0; j < 4; ++j) v[j] = (base + j < n) ? a[base + j] : 0;
    s[t] = v[0] + v[1] + v[2] + v[3];
    __syncthreads();
    for (int off = 1; off < 256; off <<= 1) {
        int x = (t >= off) ? s[t - off] : 0;
        __syncthreads();
        s[t] += x;
        __syncthreads();
    }
    if (t == 255) bsum[blk] = s[255];
    int run = (t > 0) ? s[t - 1] : 0;
#pragma unroll
    for (int j = 0; j < 4; ++j) {
        if (base + j < n) a[base + j] = run;
        run += v[j];
    }
}

__global__ __launch_bounds__(512) void scan2m_k(
    int* __restrict__ bsU, int nbU, int* __restrict__ bsI, int nbI)
{
    __shared__ int s[512];
    int* bsum = blockIdx.x ? bsI : bsU;
    int nb = blockIdx.x ? nbI : nbU;
    int t = threadIdx.x;
    int v = (t < nb) ? bsum[t] : 0;
    s[t] = v;
    __syncthreads();
    for (int off = 1; off < 512; off <<= 1) {
        int x = (t >= off) ? s[t - off] : 0;
        __syncthreads();
        s[t] += x;
        __syncthreads();
    }
    if (t < nb) bsum[t] = s[t] - v;
}

__global__ __launch_bounds__(256) void scan3m_k(
    int* __restrict__ aU, int nUe, const int* __restrict__ bsU, int nb1U,
    int* __restrict__ aI, int nIe, const int* __restrict__ bsI)
{
    int sideB = (int)blockIdx.x >= nb1U;
    int blk = sideB ? blockIdx.x - nb1U : blockIdx.x;
    int* a = sideB ? aI : aU;
    int n = sideB ? nIe : nUe;
    int add = (sideB ? bsI : bsU)[blk];
    int base = blk * 1024 + threadIdx.x * 4;
#pragma unroll
    for (int j = 0; j < 4; ++j)
        if (base + j < n) a[base + j] += add;
}

// ---------------------------------------------------------------------------
// level-1 scatter: (key,col) + val/64(bf16) into tmp (no eid indirection)
// ---------------------------------------------------------------------------
__global__ __launch_bounds__(256) void scat_k(
    const int* __restrict__ keys, const int* __restrict__ cols,
    const float* __restrict__ vals, const int* __restrict__ gh, int nb,
    int2* __restrict__ tmpb, unsigned short* __restrict__ tmpv)
{
    __shared__ int cur[512];
    for (int i = threadIdx.x; i < nb; i += 256) cur[i] = gh[i * NBLK + blockIdx.x];
    __syncthreads();
    int base = blockIdx.x * EPB;
    int end = min(base + EPB, NNZ_N);
    for (int e = base + threadIdx.x; e < end; e += 256) {
        int k = keys[e];
        int pos = atomicAdd(&cur[k >> 10], 1);
        tmpb[pos] = make_int2(k, cols[e]);
        tmpv[pos] = f2bf(vals[e] * 0.015625f);   // val/64 (fp8 dequant folded)
    }
}

// ---------------------------------------------------------------------------
// level-2 counting sort: pure sequential reads, no gathers
// ---------------------------------------------------------------------------
__global__ __launch_bounds__(256) void l2sort_k(
    const int2* __restrict__ tmpb, const unsigned short* __restrict__ tmpv,
    const int* __restrict__ gh, int nb, int* __restrict__ ptr, int nrows,
    int* __restrict__ ecol, unsigned short* __restrict__ eval)
{
    __shared__ int hist[1024];
    __shared__ int ssc[256];
    int b = blockIdx.x;
    int t = threadIdx.x;
    int bucket_base = gh[b * NBLK];
    int bucket_end  = (b == nb - 1) ? NNZ_N : gh[(b + 1) * NBLK];
    for (int i = t; i < 1024; i += 256) hist[i] = 0;
    __syncthreads();
    for (int e = bucket_base + t; e < bucket_end; e += 256)
        atomicAdd(&hist[tmpb[e].x & 1023], 1);
    __syncthreads();
    int v0 = hist[t * 4], v1 = hist[t * 4 + 1], v2 = hist[t * 4 + 2], v3 = hist[t * 4 + 3];
    ssc[t] = v0 + v1 + v2 + v3;
    __syncthreads();
    for (int off = 1; off < 256; off <<= 1) {
        int x = (t >= off) ? ssc[t - off] : 0;
        __syncthreads();
        ssc[t] += x;
        __syncthreads();
    }
    int run = (t > 0) ? ssc[t - 1] : 0;
    int g0 = run, g1 = run + v0, g2 = g1 + v1, g3 = g2 + v2;
    hist[t * 4] = g0; hist[t * 4 + 1] = g1; hist[t * 4 + 2] = g2; hist[t * 4 + 3] = g3;
    int rbase = b << 10;
    if (rbase + t * 4 < nrows)     ptr[rbase + t * 4]     = bucket_base + g0;
    if (rbase + t * 4 + 1 < nrows) ptr[rbase + t * 4 + 1] = bucket_base + g1;
    if (rbase + t * 4 + 2 < nrows) ptr[rbase + t * 4 + 2] = bucket_base + g2;
    if (rbase + t * 4 + 3 < nrows) ptr[rbase + t * 4 + 3] = bucket_base + g3;
    if (b == nb - 1 && t == 0) ptr[nrows] = NNZ_N;
    __syncthreads();
    for (int e = bucket_base + t; e < bucket_end; e += 256) {
        int2 q = tmpb[e];
        int pos = bucket_base + atomicAdd(&hist[q.x & 1023], 1);
        ecol[pos] = q.y;
        eval[pos] = tmpv[e];
    }
}

// ---------------------------------------------------------------------------
// dual-side CSR SpMM (both sides in one dispatch), fp8 gathers + HW cvt.
// MODE 0: o = relu(A@x + base*deg); write bf16 + fp8.
// MODE 1: o = relu(...); out = w0*embed + w1*base + w2*o; accumulate sum^2.
// ---------------------------------------------------------------------------
template <int MODE>
__global__ __launch_bounds__(256) void spmm_dual_k(
    int gA,
    const int* __restrict__ ptrA, const int* __restrict__ ecolA, const unsigned short* __restrict__ evalA,
    const unsigned char* __restrict__ x8A, const unsigned short* baseA, const float* __restrict__ degA,
    unsigned short* outA, int nA, unsigned char* __restrict__ out8A,
    const unsigned short* embedA, float* __restrict__ accA,
    const int* __restrict__ ptrB, const int* __restrict__ ecolB, const unsigned short* __restrict__ evalB,
    const unsigned char* __restrict__ x8B, const unsigned short* baseB, const float* __restrict__ degB,
    unsigned short* outB, int nB, unsigned char* __restrict__ out8B,
    const unsigned short* embedB, float* __restrict__ accB,
    const float* __restrict__ add_w)
{
    int wv = threadIdx.x >> 6, lane = threadIdx.x & 63;
    int bid = blockIdx.x;
    int sideB = bid >= gA;
    int lb = sideB ? bid - gA : bid;
    const int* ptr = sideB ? ptrB : ptrA;
    const int* ecol = sideB ? ecolB : ecolA;
    const unsigned short* eval = sideB ? evalB : evalA;
    const unsigned char* x8 = sideB ? x8B : x8A;
    const unsigned short* base = sideB ? baseB : baseA;
    const float* deg = sideB ? degB : degA;
    unsigned short* out = sideB ? outB : outA;
    int nrows = sideB ? nB : nA;
    __shared__ float ssum[4];
    int r = lb * 4 + wv;
    if (r < nrows) {
        int s0 = __builtin_amdgcn_readfirstlane(ptr[r]);
        int e0 = __builtin_amdgcn_readfirstlane(ptr[r + 1]);
        float a0 = 0.f, a1 = 0.f, a2 = 0.f, a3 = 0.f;
        int k = s0;
        for (; k + 8 <= e0; k += 8) {
            int c0 = ecol[k],     c1 = ecol[k + 1], c2 = ecol[k + 2], c3 = ecol[k + 3];
            int c4 = ecol[k + 4], c5 = ecol[k + 5], c6 = ecol[k + 6], c7 = ecol[k + 7];
            unsigned char b0 = x8[(size_t)c0 * DDIM + lane];
            unsigned char b1 = x8[(size_t)c1 * DDIM + lane];
            unsigned char b2 = x8[(size_t)c2 * DDIM + lane];
            unsigned char b3 = x8[(size_t)c3 * DDIM + lane];
            unsigned char b4 = x8[(size_t)c4 * DDIM + lane];
            unsigned char b5 = x8[(size_t)c5 * DDIM + lane];
            unsigned char b6 = x8[(size_t)c6 * DDIM + lane];
            unsigned char b7 = x8[(size_t)c7 * DDIM + lane];
            a0 = fmaf(bf2f(eval[k]),     FP8DEC(b0), a0);
            a1 = fmaf(bf2f(eval[k + 1]), FP8DEC(b1), a1);
            a2 = fmaf(bf2f(eval[k + 2]), FP8DEC(b2), a2);
            a3 = fmaf(bf2f(eval[k + 3]), FP8DEC(b3), a3);
            a0 = fmaf(bf2f(eval[k + 4]), FP8DEC(b4), a0);
            a1 = fmaf(bf2f(eval[k + 5]), FP8DEC(b5), a1);
            a2 = fmaf(bf2f(eval[k + 6]), FP8DEC(b6), a2);
            a3 = fmaf(bf2f(eval[k + 7]), FP8DEC(b7), a3);
        }
        for (; k + 4 <= e0; k += 4) {
            int c0 = ecol[k], c1 = ecol[k + 1], c2 = ecol[k + 2], c3 = ecol[k + 3];
            unsigned char b0 = x8[(size_t)c0 * DDIM + lane];
            unsigned char b1 = x8[(size_t)c1 * DDIM + lane];
            unsigned char b2 = x8[(size_t)c2 * DDIM + lane];
            unsigned char b3 = x8[(size_t)c3 * DDIM + lane];
            a0 = fmaf(bf2f(eval[k]),     FP8DEC(b0), a0);
            a1 = fmaf(bf2f(eval[k + 1]), FP8DEC(b1), a1);
            a2 = fmaf(bf2f(eval[k + 2]), FP8DEC(b2), a2);
            a3 = fmaf(bf2f(eval[k + 3]), FP8DEC(b3), a3);
        }
        for (; k < e0; ++k)
            a0 = fmaf(bf2f(eval[k]), FP8DEC(x8[(size_t)ecol[k] * DDIM + lane]), a0);
        float acc = (a0 + a1) + (a2 + a3);
        float bb = bf2f(base[(size_t)r * DDIM + lane]);
        float o = fmaxf(fmaf(bb, deg[r], acc), 0.f);
        if (MODE == 0) {
            out[(size_t)r * DDIM + lane] = f2bf(o);
            (sideB ? out8B : out8A)[(size_t)r * DDIM + lane] = f2fp8(o);
        } else {
            const unsigned short* embed = sideB ? embedB : embedA;
            float g = fmaf(add_w[0], bf2f(embed[(size_t)r * DDIM + lane]),
                           fmaf(add_w[1], bb, add_w[2] * o));
            out[(size_t)r * DDIM + lane] = f2bf(g);
            float sq = g * g;
            for (int off = 32; off; off >>= 1) sq += __shfl_down(sq, off);
            if (lane == 0) ssum[wv] = sq;
        }
    } else if (MODE == 1) {
        if (lane == 0) ssum[wv] = 0.f;
    }
    if (MODE == 1) {
        __syncthreads();
        if (threadIdx.x == 0)
            atomicAdd(&(sideB ? accB : accA)[lb & (ACC_SLOTS - 1)],
                      ssum[0] + ssum[1] + ssum[2] + ssum[3]);
    }
}

// ---------------------------------------------------------------------------
// MLP as block-tiled VALU GEMM (unchanged)
// ---------------------------------------------------------------------------
__global__ __launch_bounds__(256) void mlp_k(
    const int* __restrict__ user0, const int* __restrict__ item0,
    const unsigned short* __restrict__ gcnU, const unsigned short* __restrict__ gcnI,
    const float* __restrict__ fw1, const float* __restrict__ fb1,
    const float* __restrict__ fw2, const float* __restrict__ fb2,
    unsigned short* __restrict__ ou, unsigned short* __restrict__ oi)
{
    __shared__ unsigned short xs[64][72];
    __shared__ unsigned short w1s[128][68];
    __shared__ unsigned short w2s[64][140];
    __shared__ unsigned short hs[128][72];
    __shared__ float b1s[128];
    __shared__ float b2s[64];

    int t = threadIdx.x;
    int side = blockIdx.x >> 9;
    int tile = blockIdx.x & 511;
    const int* sel = side ? item0 : user0;
    const unsigned short* gcn = side ? gcnI : gcnU;
    unsigned short* outp = side ? oi : ou;

    {
        int r = t >> 2, c = t & 3;
        int idx = sel[tile * 64 + r];
        const ushort4* src = (const ushort4*)(gcn + (size_t)idx * 64 + c * 16);
        ushort4 v0 = src[0], v1 = src[1], v2 = src[2], v3 = src[3];
        int k0 = c * 16;
        xs[k0 +  0][r] = v0.x; xs[k0 +  1][r] = v0.y; xs[k0 +  2][r] = v0.z; xs[k0 +  3][r] = v0.w;
        xs[k0 +  4][r] = v1.x; xs[k0 +  5][r] = v1.y; xs[k0 +  6][r] = v1.z; xs[k0 +  7][r] = v1.w;
        xs[k0 +  8][r] = v2.x; xs[k0 +  9][r] = v2.y; xs[k0 + 10][r] = v2.z; xs[k0 + 11][r] = v2.w;
        xs[k0 + 12][r] = v3.x; xs[k0 + 13][r] = v3.y; xs[k0 + 14][r] = v3.z; xs[k0 + 15][r] = v3.w;
    }
#pragma unroll
    for (int i = 0; i < 8; ++i) {
        int flat = i * 1024 + t * 4;
        float4 w = *(const float4*)(fw1 + flat);
        int o = flat >> 6, k = flat & 63;
        *(unsigned*)&w1s[o][k]     = (unsigned)f2bf(w.x) | ((unsigned)f2bf(w.y) << 16);
        *(unsigned*)&w1s[o][k + 2] = (unsigned)f2bf(w.z) | ((unsigned)f2bf(w.w) << 16);
        float4 u = *(const float4*)(fw2 + flat);
        int o2 = flat >> 7, k2 = flat & 127;
        *(unsigned*)&w2s[o2][k2]     = (unsigned)f2bf(u.x) | ((unsigned)f2bf(u.y) << 16);
        *(unsigned*)&w2s[o2][k2 + 2] = (unsigned)f2bf(u.z) | ((unsigned)f2bf(u.w) << 16);
    }
    if (t < 128) b1s[t] = fb1[t];
    if (t < 64)  b2s[t] = fb2[t];
    __syncthreads();

    int sg = t & 15, og = t >> 4;

    float acc[4][8];
#pragma unroll
    for (int i = 0; i < 4; ++i)
#pragma unroll
        for (int j = 0; j < 8; ++j) acc[i][j] = 0.f;

    for (int kc = 0; kc < 64; kc += 4) {
        uint2 xp0 = *(const uint2*)&xs[kc    ][sg * 4];
        uint2 xp1 = *(const uint2*)&xs[kc + 1][sg * 4];
        uint2 xp2 = *(const uint2*)&xs[kc + 2][sg * 4];
        uint2 xp3 = *(const uint2*)&xs[kc + 3][sg * 4];
        float x0[4] = { bflo(xp0.x), bfhi(xp0.x), bflo(xp0.y), bfhi(xp0.y) };
        float x1[4] = { bflo(xp1.x), bfhi(xp1.x), bflo(xp1.y), bfhi(xp1.y) };
        float x2[4] = { bflo(xp2.x), bfhi(xp2.x), bflo(xp2.y), bfhi(xp2.y) };
        float x3[4] = { bflo(xp3.x), bfhi(xp3.x), bflo(xp3.y), bfhi(xp3.y) };
#pragma unroll
        for (int j = 0; j < 8; ++j) {
            uint2 wp = *(const uint2*)&w1s[og * 8 + j][kc];
            float w0 = bflo(wp.x), w1v = bfhi(wp.x), w2v = bflo(wp.y), w3v = bfhi(wp.y);
#pragma unroll
            for (int i = 0; i < 4; ++i) {
                acc[i][j] = fmaf(x0[i], w0,  acc[i][j]);
                acc[i][j] = fmaf(x1[i], w1v, acc[i][j]);
                acc[i][j] = fmaf(x2[i], w2v, acc[i][j]);
                acc[i][j] = fmaf(x3[i], w3v, acc[i][j]);
            }
        }
    }
#pragma unroll
    for (int j = 0; j < 8; ++j) {
        int o = og * 8 + j;
        float b = b1s[o];
        float h0 = leaky(acc[0][j] + b), h1 = leaky(acc[1][j] + b);
        float h2 = leaky(acc[2][j] + b), h3 = leaky(acc[3][j] + b);
        *(unsigned*)&hs[o][sg * 4]     = (unsigned)f2bf(h0) | ((unsigned)f2bf(h1) << 16);
        *(unsigned*)&hs[o][sg * 4 + 2] = (unsigned)f2bf(h2) | ((unsigned)f2bf(h3) << 16);
    }
    __syncthreads();

    float acc2[4][4];
#pragma unroll
    for (int i = 0; i < 4; ++i)
#pragma unroll
        for (int j = 0; j < 4; ++j) acc2[i][j] = 0.f;

    for (int kc = 0; kc < 128; kc += 4) {
        uint2 hp0 = *(const uint2*)&hs[kc    ][sg * 4];
        uint2 hp1 = *(const uint2*)&hs[kc + 1][sg * 4];
        uint2 hp2 = *(const uint2*)&hs[kc + 2][sg * 4];
        uint2 hp3 = *(const uint2*)&hs[kc + 3][sg * 4];
        float h0[4] = { bflo(hp0.x), bfhi(hp0.x), bflo(hp0.y), bfhi(hp0.y) };
        float h1[4] = { bflo(hp1.x), bfhi(hp1.x), bflo(hp1.y), bfhi(hp1.y) };
        float h2[4] = { bflo(hp2.x), bfhi(hp2.x), bflo(hp2.y), bfhi(hp2.y) };
        float h3[4] = { bflo(hp3.x), bfhi(hp3.x), bflo(hp3.y), bfhi(hp3.y) };
#pragma unroll
        for (int j = 0; j < 4; ++j) {
            uint2 wp = *(const uint2*)&w2s[og * 4 + j][kc];
            float w0 = bflo(wp.x), w1v = bfhi(wp.x), w2v = bflo(wp.y), w3v = bfhi(wp.y);
#pragma unroll
            for (int i = 0; i < 4; ++i) {
                acc2[i][j] = fmaf(h0[i], w0,  acc2[i][j]);
                acc2[i][j] = fmaf(h1[i], w1v, acc2[i][j]);
                acc2[i][j] = fmaf(h2[i], w2v, acc2[i][j]);
                acc2[i][j] = fmaf(h3[i], w3v, acc2[i][j]);
            }
        }
    }
#pragma unroll
    for (int i = 0; i < 4; ++i) {
        float o0 = leaky(acc2[i][0] + b2s[og * 4 + 0]);
        float o1 = leaky(acc2[i][1] + b2s[og * 4 + 1]);
        float o2 = leaky(acc2[i][2] + b2s[og * 4 + 2]);
        float o3 = leaky(acc2[i][3] + b2s[og * 4 + 3]);
        uint2 pp;
        pp.x = (unsigned)f2bf(o0) | ((unsigned)f2bf(o1) << 16);
        pp.y = (unsigned)f2bf(o2) | ((unsigned)f2bf(o3) << 16);
        *(uint2*)(outp + ((size_t)(tile * 64 + sg * 4 + i) * 64 + og * 4)) = pp;
    }
}

// ---------------------------------------------------------------------------
__global__ __launch_bounds__(256) void dot_sse_k(
    const unsigned short* __restrict__ ou, const unsigned short* __restrict__ oi,
    const int* __restrict__ user0, const int* __restrict__ item0,
    const float* __restrict__ ub, const float* __restrict__ ib,
    const float* __restrict__ avg, const float* __restrict__ ratings,
    float* __restrict__ sse)
{
    int g = blockIdx.x * 256 + threadIdx.x;
    int b = g >> 2, q = g & 3;
    const uint4* pu = (const uint4*)(ou + (size_t)b * 64 + q * 16);
    const uint4* pi = (const uint4*)(oi + (size_t)b * 64 + q * 16);
    uint4 a0 = pu[0], a1 = pu[1];
    uint4 c0 = pi[0], c1 = pi[1];
    float s = 0.f;
#define DOTP(ua, uc) { s = fmaf(bflo(ua), bflo(uc), s); s = fmaf(bfhi(ua), bfhi(uc), s); }
    DOTP(a0.x, c0.x) DOTP(a0.y, c0.y) DOTP(a0.z, c0.z) DOTP(a0.w, c0.w)
    DOTP(a1.x, c1.x) DOTP(a1.y, c1.y) DOTP(a1.z, c1.z) DOTP(a1.w, c1.w)
#undef DOTP
    s += __shfl_xor(s, 1);
    s += __shfl_xor(s, 2);
    float contrib = 0.f;
    if (q == 0) {
        float pred = s + ub[user0[b]] + ib[item0[b]] + avg[0];
        float d = pred - ratings[b];
        contrib = d * d;
    }
    for (int off = 32; off; off >>= 1) contrib += __shfl_down(contrib, off);
    __shared__ float wsum[4];
    int lane = threadIdx.x & 63, wv = threadIdx.x >> 6;
    if (lane == 0) wsum[wv] = contrib;
    __syncthreads();
    if (threadIdx.x == 0)
        atomicAdd(sse, wsum[0] + wsum[1] + wsum[2] + wsum[3]);
}

__global__ __launch_bounds__(256) void finalize2_k(
    const float* __restrict__ accU, const float* __restrict__ accI,
    const float* __restrict__ sse, float* __restrict__ out)
{
    int t = threadIdx.x;
    float su = 0.f, si = 0.f;
    for (int i = t; i < ACC_SLOTS; i += 256) { su += accU[i]; si += accI[i]; }
    for (int off = 32; off; off >>= 1) {
        su += __shfl_down(su, off);
        si += __shfl_down(si, off);
    }
    __shared__ float s[8];
    int wv = t >> 6, lane = t & 63;
    if (lane == 0) { s[wv] = su; s[wv + 4] = si; }
    __syncthreads();
    if (t == 0) {
        float SU = s[0] + s[1] + s[2] + s[3];
        float SI = s[4] + s[5] + s[6] + s[7];
        out[0] = sse[0] / (float)BATCH
               + LAM_F * (SU / (float)((double)U_NUM * 64.0))
               + LAM_F * (SI / (float)((double)I_NUM * 64.0));
    }
}

// ---------------------------------------------------------------------------

extern "C" void kernel_launch(void* const* d_in, const int* in_sizes, int n_in,
                              void* d_out, int out_size, void* d_ws, size_t ws_size,
                              hipStream_t stream)
{
    const int*   ui_rows = (const int*)d_in[0];
    const int*   ui_cols = (const int*)d_in[1];
    const float* ui_vals = (const float*)d_in[2];
    const float* iu_vals = (const float*)d_in[3];
    const float* d_i     = (const float*)d_in[4];
    const float* d_j     = (const float*)d_in[5];
    const float* eu      = (const float*)d_in[6];
    const float* ei      = (const float*)d_in[7];
    const float* add_w   = (const float*)d_in[8];
    const float* fw1     = (const float*)d_in[9];
    const float* fb1     = (const float*)d_in[10];
    const float* fw2     = (const float*)d_in[11];
    const float* fb2     = (const float*)d_in[12];
    const float* ub      = (const float*)d_in[13];
    const float* ib      = (const float*)d_in[14];
    const float* avg     = (const float*)d_in[15];
    const int*   user0   = (const int*)d_in[16];
    const int*   item0   = (const int*)d_in[17];
    const float* ratings = (const float*)d_in[18];

    const size_t U64 = (size_t)U_NUM * DDIM;
    const size_t I64 = (size_t)I_NUM * DDIM;

    // ---- workspace layout (~320 MB; known-safe budget >= 334 MB) ----
    int*            ecol_u = (int*)d_ws;                        // NNZ
    unsigned short* eval_u = (unsigned short*)(ecol_u + NNZ_N); // NNZ
    int*            ecol_i = (int*)(eval_u + NNZ_N);            // NNZ
    unsigned short* eval_i = (unsigned short*)(ecol_i + NNZ_N); // NNZ
    int2*           tmpb   = (int2*)(eval_i + NNZ_N);           // NNZ (32MB)
    unsigned short* tmpv   = (unsigned short*)(tmpb + NNZ_N);   // NNZ (8MB)
    // overlay inside tmpb (dead after l2sort): g1u_f8 + ou/oi
    unsigned char*  g1u_f8 = (unsigned char*)tmpb;              // U64 B
    unsigned short* ou_bf  = (unsigned short*)(g1u_f8 + ((U64 + 15) & ~15ull));
    unsigned short* oi_bf  = ou_bf + (size_t)BATCH * 64;
    int*  gh_u  = (int*)(tmpv + NNZ_N);                         // NB_U*NBLK
    int*  gh_i  = gh_u + (size_t)NB_U * NBLK;                   // NB_I*NBLK
    int*  bsumU = gh_i + (size_t)NB_I * NBLK;                   // 512
    int*  bsumI = bsumU + 512;                                  // 512
    int*  ptr_u = bsumI + 512;                                  // U+1
    int*  ptr_i = ptr_u + (U_NUM + 1);                          // I+1
    float* accU = (float*)(ptr_i + (I_NUM + 1));                // ACC_SLOTS
    float* accI = accU + ACC_SLOTS;                             // ACC_SLOTS
    float* sse  = accI + ACC_SLOTS;                             // 4
    unsigned short* eu_bf  = (unsigned short*)(sse + 4);        // U64
    unsigned short* ei_bf  = eu_bf + U64;                       // I64 (becomes gcnI)
    unsigned short* g1u_bf = ei_bf + I64;                       // U64 (becomes gcnU)
    unsigned short* g1i_bf = g1u_bf + U64;                      // I64
    unsigned char*  eu_f8  = (unsigned char*)(g1i_bf + I64);    // U64 B
    unsigned char*  ei_f8  = eu_f8 + U64;                       // I64 B
    unsigned char*  g1i_f8 = ei_f8 + I64;                       // I64 B
    (void)ws_size;

    dim3 blk(256);
    int gu = (U_NUM + 3) / 4, gi = (I_NUM + 3) / 4;
    int nUe = NB_U * NBLK, nIe = NB_I * NBLK;
    int nb1U = (nUe + 1023) / 1024, nb1I = (nIe + 1023) / 1024;

    // zero hist + acc region (gh_u .. sse+4, contiguous)
    size_t meta_bytes = ((char*)(sse + 4)) - (char*)gh_u;
    hipMemsetAsync(gh_u, 0, meta_bytes, stream);

    f2bf8_k<<<2048, blk, 0, stream>>>((const float4*)eu, (ushort4*)eu_bf, (uchar4*)eu_f8,
                                      (const float4*)ei, (ushort4*)ei_bf, (uchar4*)ei_f8,
                                      U64 / 4, (U64 + I64) / 4);

    hist2_k<<<2 * NBLK, blk, 0, stream>>>(ui_rows, ui_cols, gh_u, gh_i);
    scan1m_k<<<nb1U + nb1I, blk, 0, stream>>>(gh_u, nUe, bsumU, nb1U, gh_i, nIe, bsumI);
    scan2m_k<<<2, 512, 0, stream>>>(bsumU, nb1U, bsumI, nb1I);
    scan3m_k<<<nb1U + nb1I, blk, 0, stream>>>(gh_u, nUe, bsumU, nb1U, gh_i, nIe, bsumI);

    // user-side scatter + sort (tmp shared, so strictly sequential)
    scat_k<<<NBLK, blk, 0, stream>>>(ui_rows, ui_cols, ui_vals, gh_u, NB_U, tmpb, tmpv);
    l2sort_k<<<NB_U, blk, 0, stream>>>(tmpb, tmpv, gh_u, NB_U, ptr_u, U_NUM, ecol_u, eval_u);
    // item-side
    scat_k<<<NBLK, blk, 0, stream>>>(ui_cols, ui_rows, iu_vals, gh_i, NB_I, tmpb, tmpv);
    l2sort_k<<<NB_I, blk, 0, stream>>>(tmpb, tmpv, gh_i, NB_I, ptr_i, I_NUM, ecol_i, eval_i);
    // tmpb dead from here: g1u_f8 / ou / oi overlay it.

    // ---- layer 1 (both sides, one dispatch) ----
    spmm_dual_k<0><<<gu + gi, blk, 0, stream>>>(gu,
        ptr_u, ecol_u, eval_u, ei_f8, eu_bf, d_i, g1u_bf, U_NUM, g1u_f8, nullptr, nullptr,
        ptr_i, ecol_i, eval_i, eu_f8, ei_bf, d_j, g1i_bf, I_NUM, g1i_f8, nullptr, nullptr,
        nullptr);
    // ---- layer 2 + combine + fused L2 (both sides, one dispatch) ----
    spmm_dual_k<1><<<gi + gu, blk, 0, stream>>>(gi,
        ptr_i, ecol_i, eval_i, g1u_f8, g1i_bf, d_j, ei_bf, I_NUM, nullptr, ei_bf, accI,
        ptr_u, ecol_u, eval_u, g1i_f8, g1u_bf, d_i, g1u_bf, U_NUM, nullptr, eu_bf, accU,
        add_w);

    mlp_k<<<1024, blk, 0, stream>>>(user0, item0, g1u_bf, ei_bf,
                                    fw1, fb1, fw2, fb2, ou_bf, oi_bf);
    dot_sse_k<<<BATCH * 4 / 256, blk, 0, stream>>>(ou_bf, oi_bf, user0, item0,
                                                   ub, ib, avg, ratings, sse);
    finalize2_k<<<1, blk, 0, stream>>>(accU, accI, sse, (float*)d_out);
}

// Round 11
// 1155.510 us; speedup vs baseline: 1.1510x; 1.0626x over previous
//
#include <hip/hip_runtime.h>

#define U_NUM 359347
#define I_NUM 292589
#define DDIM  64
#define NNZ_N 4000000
#define BATCH 32768
#define LAM_F 0.001f
#define ACC_SLOTS 2048

#define EPB   4096
#define NBLK  ((NNZ_N + EPB - 1) / EPB)     // 977
#define NB_U  ((U_NUM + 1023) >> 10)        // 351
#define NB_I  ((I_NUM + 1023) >> 10)        // 286

__device__ __forceinline__ float leaky(float x) { return x > 0.f ? x : 0.1f * x; }

__device__ __forceinline__ unsigned short f2bf(float f) {
    unsigned b = __float_as_uint(f);
    b = (b + 0x7FFF + ((b >> 16) & 1)) >> 16;   // RNE
    return (unsigned short)b;
}
__device__ __forceinline__ float bf2f(unsigned short u) {
    return __uint_as_float((unsigned)u << 16);
}
__device__ __forceinline__ float bflo(unsigned u) { return __uint_as_float(u << 16); }
__device__ __forceinline__ float bfhi(unsigned u) { return __uint_as_float(u & 0xffff0000u); }

// ---- fp8 e4m3fn (OCP, bias 7), global scale 64 folded at encode ----
__device__ __forceinline__ unsigned char f2fp8(float v) {
    v = fminf(fmaxf(v * 64.f, -440.f), 440.f);
    unsigned b = __float_as_uint(v * 0x1p-120f);
    unsigned sign = (b >> 24) & 0x80u;
    unsigned mag = b & 0x7fffffffu;
    mag += 0x7ffffu + ((mag >> 20) & 1u);
    return (unsigned char)(sign | ((mag >> 20) & 0x7fu));
}
// decode WITHOUT 1/64 (scale folded elsewhere): returns 64 * true_value
#if __has_builtin(__builtin_amdgcn_cvt_f32_fp8)
#define FP8DEC(b) __builtin_amdgcn_cvt_f32_fp8((int)(b), 0)
#else
#define FP8DEC(b) (__uint_as_float(((unsigned)((b) & 0x80u) << 24) | \
                                   ((unsigned)((b) & 0x7fu) << 20)) * 0x1p120f)
#endif
#define INV64 0.015625f

// ---------------------------------------------------------------------------
// fp32 -> fp8 (both embeddings, one launch)
// ---------------------------------------------------------------------------
__global__ __launch_bounds__(256) void f2f8_k(
    const float4* __restrict__ inU, uchar4* __restrict__ o8U,
    const float4* __restrict__ inI, uchar4* __restrict__ o8I,
    size_t nU4, size_t total4)
{
    size_t stride = (size_t)gridDim.x * 256;
    for (size_t i = (size_t)blockIdx.x * 256 + threadIdx.x; i < total4; i += stride) {
        const float4* in; uchar4* o8; size_t j;
        if (i < nU4) { in = inU; o8 = o8U; j = i; }
        else         { in = inI; o8 = o8I; j = i - nU4; }
        float4 v = in[j];
        uchar4 p;
        p.x = f2fp8(v.x); p.y = f2fp8(v.y); p.z = f2fp8(v.z); p.w = f2fp8(v.w);
        o8[j] = p;
    }
}

// ---------------------------------------------------------------------------
// hist both sides (bucket = key >> 10)
// ---------------------------------------------------------------------------
__global__ __launch_bounds__(256) void hist2_k(
    const int* __restrict__ rows, const int* __restrict__ cols,
    int* __restrict__ gh_u, int* __restrict__ gh_i)
{
    __shared__ int h[512];
    int sideB = blockIdx.x >= NBLK;
    int blk = sideB ? blockIdx.x - NBLK : blockIdx.x;
    const int* keys = sideB ? cols : rows;
    int nb = sideB ? NB_I : NB_U;
    int* gh = sideB ? gh_i : gh_u;
    for (int i = threadIdx.x; i < nb; i += 256) h[i] = 0;
    __syncthreads();
    int base = blk * EPB;
    int end = min(base + EPB, NNZ_N);
    for (int e = base + threadIdx.x; e < end; e += 256)
        atomicAdd(&h[keys[e] >> 10], 1);
    __syncthreads();
    for (int i = threadIdx.x; i < nb; i += 256)
        gh[i * NBLK + blk] = h[i];
}

// ---------------------------------------------------------------------------
// merged scans
// ---------------------------------------------------------------------------
__global__ __launch_bounds__(256) void scan1m_k(
    int* __restrict__ aU, int nUe, int* __restrict__ bsU, int nb1U,
    int* __restrict__ aI, int nIe, int* __restrict__ bsI)
{
    __shared__ int s[256];
    int sideB = (int)blockIdx.x >= nb1U;
    int blk = sideB ? blockIdx.x - nb1U : blockIdx.x;
    int* a = sideB ? aI : aU;
    int n = sideB ? nIe : nUe;
    int* bsum = sideB ? bsI : bsU;
    int t = threadIdx.x;
    int base = blk * 1024 + t * 4;
    int v[4];
#pragma unroll
    for (int j = 0; j < 4; ++j) v[j] = (base + j < n) ? a[base + j] : 0;
    s[t] = v[0] + v[1] + v[2] + v[3];
    __syncthreads();
    for (int off = 1; off < 256; off <<= 1) {
        int x = (t >= off) ? s[t - off] : 0;
        __syncthreads();
        s[t] += x;
        __syncthreads();
    }
    if (t == 255) bsum[blk] = s[255];
    int run = (t > 0) ? s[t - 1] : 0;
#pragma unroll
    for (int j = 0; j < 4; ++j) {
        if (base + j < n) a[base + j] = run;
        run += v[j];
    }
}

__global__ __launch_bounds__(512) void scan2m_k(
    int* __restrict__ bsU, int nbU, int* __restrict__ bsI, int nbI)
{
    __shared__ int s[512];
    int* bsum = blockIdx.x ? bsI : bsU;
    int nb = blockIdx.x ? nbI : nbU;
    int t = threadIdx.x;
    int v = (t < nb) ? bsum[t] : 0;
    s[t] = v;
    __syncthreads();
    for (int off = 1; off < 512; off <<= 1) {
        int x = (t >= off) ? s[t - off] : 0;
        __syncthreads();
        s[t] += x;
        __syncthreads();
    }
    if (t < nb) bsum[t] = s[t] - v;
}

__global__ __launch_bounds__(256) void scan3m_k(
    int* __restrict__ aU, int nUe, const int* __restrict__ bsU, int nb1U,
    int* __restrict__ aI, int nIe, const int* __restrict__ bsI)
{
    int sideB = (int)blockIdx.x >= nb1U;
    int blk = sideB ? blockIdx.x - nb1U : blockIdx.x;
    int* a = sideB ? aI : aU;
    int n = sideB ? nIe : nUe;
    int add = (sideB ? bsI : bsU)[blk];
    int base = blk * 1024 + threadIdx.x * 4;
#pragma unroll
    for (int j = 0; j < 4; ++j)
        if (base + j < n) a[base + j] += add;
}

// ---------------------------------------------------------------------------
// dual level-1 scatter: packed uint (col<<10 | key&1023) + val/64 bf16
// ---------------------------------------------------------------------------
__global__ __launch_bounds__(256) void scat2_k(
    const int* __restrict__ rows, const int* __restrict__ cols,
    const float* __restrict__ uv, const float* __restrict__ iv,
    const int* __restrict__ gh_u, const int* __restrict__ gh_i,
    unsigned* __restrict__ tc_u, unsigned short* __restrict__ tv_u,
    unsigned* __restrict__ tc_i, unsigned short* __restrict__ tv_i)
{
    __shared__ int cur[512];
    int sideB = blockIdx.x >= NBLK;
    int blk = sideB ? blockIdx.x - NBLK : blockIdx.x;
    const int* keys = sideB ? cols : rows;
    const int* other = sideB ? rows : cols;
    const float* vals = sideB ? iv : uv;
    const int* gh = sideB ? gh_i : gh_u;
    int nb = sideB ? NB_I : NB_U;
    unsigned* tc = sideB ? tc_i : tc_u;
    unsigned short* tv = sideB ? tv_i : tv_u;
    for (int i = threadIdx.x; i < nb; i += 256) cur[i] = gh[i * NBLK + blk];
    __syncthreads();
    int base = blk * EPB;
    int end = min(base + EPB, NNZ_N);
    for (int e = base + threadIdx.x; e < end; e += 256) {
        int k = keys[e];
        int pos = atomicAdd(&cur[k >> 10], 1);
        tc[pos] = ((unsigned)other[e] << 10) | (unsigned)(k & 1023);
        tv[pos] = f2bf(vals[e] * INV64);
    }
}

// ---------------------------------------------------------------------------
// dual level-2 counting sort (sequential reads only)
// ---------------------------------------------------------------------------
__global__ __launch_bounds__(256) void l2sort2_k(
    const unsigned* __restrict__ tc_u, const unsigned short* __restrict__ tv_u,
    const unsigned* __restrict__ tc_i, const unsigned short* __restrict__ tv_i,
    const int* __restrict__ gh_u, const int* __restrict__ gh_i,
    int* __restrict__ ptr_u, int* __restrict__ ptr_i,
    int* __restrict__ ecol_u, unsigned short* __restrict__ eval_u,
    int* __restrict__ ecol_i, unsigned short* __restrict__ eval_i)
{
    __shared__ int hist[1024];
    __shared__ int ssc[256];
    int sideB = blockIdx.x >= NB_U;
    int b = sideB ? blockIdx.x - NB_U : blockIdx.x;
    const unsigned* tc = sideB ? tc_i : tc_u;
    const unsigned short* tv = sideB ? tv_i : tv_u;
    const int* gh = sideB ? gh_i : gh_u;
    int nb = sideB ? NB_I : NB_U;
    int nrows = sideB ? I_NUM : U_NUM;
    int* ptr = sideB ? ptr_i : ptr_u;
    int* ecol = sideB ? ecol_i : ecol_u;
    unsigned short* eval = sideB ? eval_i : eval_u;
    int t = threadIdx.x;
    int bucket_base = gh[b * NBLK];
    int bucket_end  = (b == nb - 1) ? NNZ_N : gh[(b + 1) * NBLK];
    for (int i = t; i < 1024; i += 256) hist[i] = 0;
    __syncthreads();
    for (int e = bucket_base + t; e < bucket_end; e += 256)
        atomicAdd(&hist[tc[e] & 1023u], 1);
    __syncthreads();
    int v0 = hist[t * 4], v1 = hist[t * 4 + 1], v2 = hist[t * 4 + 2], v3 = hist[t * 4 + 3];
    ssc[t] = v0 + v1 + v2 + v3;
    __syncthreads();
    for (int off = 1; off < 256; off <<= 1) {
        int x = (t >= off) ? ssc[t - off] : 0;
        __syncthreads();
        ssc[t] += x;
        __syncthreads();
    }
    int run = (t > 0) ? ssc[t - 1] : 0;
    int g0 = run, g1 = run + v0, g2 = g1 + v1, g3 = g2 + v2;
    hist[t * 4] = g0; hist[t * 4 + 1] = g1; hist[t * 4 + 2] = g2; hist[t * 4 + 3] = g3;
    int rbase = b << 10;
    if (rbase + t * 4 < nrows)     ptr[rbase + t * 4]     = bucket_base + g0;
    if (rbase + t * 4 + 1 < nrows) ptr[rbase + t * 4 + 1] = bucket_base + g1;
    if (rbase + t * 4 + 2 < nrows) ptr[rbase + t * 4 + 2] = bucket_base + g2;
    if (rbase + t * 4 + 3 < nrows) ptr[rbase + t * 4 + 3] = bucket_base + g3;
    if (b == nb - 1 && t == 0) ptr[nrows] = NNZ_N;
    __syncthreads();
    for (int e = bucket_base + t; e < bucket_end; e += 256) {
        unsigned q = tc[e];
        int pos = bucket_base + atomicAdd(&hist[q & 1023u], 1);
        ecol[pos] = (int)(q >> 10);
        eval[pos] = tv[e];
    }
}

// ---------------------------------------------------------------------------
// dual CSR SpMM, all-fp8 feature path.
// MODE 0: o = relu(A@x + base*deg); write fp8 only.
// MODE 1: o = relu(A@x + base*deg); gcn = w0*emb + w1*base + w2*o (bf16 out);
//         accumulate sum(gcn^2).
// base8/emb8 decode to 64x true value; scales folded via INV64.
// ---------------------------------------------------------------------------
template <int MODE>
__global__ __launch_bounds__(256) void spmm_dual_k(
    int gA,
    const int* __restrict__ ptrA, const int* __restrict__ ecolA, const unsigned short* __restrict__ evalA,
    const unsigned char* __restrict__ x8A, const unsigned char* __restrict__ base8A,
    const float* __restrict__ degA, int nA,
    unsigned char* __restrict__ out8A, unsigned short* __restrict__ outbA,
    const unsigned char* __restrict__ emb8A, float* __restrict__ accA,
    const int* __restrict__ ptrB, const int* __restrict__ ecolB, const unsigned short* __restrict__ evalB,
    const unsigned char* __restrict__ x8B, const unsigned char* __restrict__ base8B,
    const float* __restrict__ degB, int nB,
    unsigned char* __restrict__ out8B, unsigned short* __restrict__ outbB,
    const unsigned char* __restrict__ emb8B, float* __restrict__ accB,
    const float* __restrict__ add_w)
{
    int wv = threadIdx.x >> 6, lane = threadIdx.x & 63;
    int bid = blockIdx.x;
    int sideB = bid >= gA;
    int lb = sideB ? bid - gA : bid;
    const int* ptr = sideB ? ptrB : ptrA;
    const int* ecol = sideB ? ecolB : ecolA;
    const unsigned short* eval = sideB ? evalB : evalA;
    const unsigned char* x8 = sideB ? x8B : x8A;
    const unsigned char* base8 = sideB ? base8B : base8A;
    const float* deg = sideB ? degB : degA;
    int nrows = sideB ? nB : nA;
    __shared__ float ssum[4];
    int r = lb * 4 + wv;
    if (r < nrows) {
        int s0 = __builtin_amdgcn_readfirstlane(ptr[r]);
        int e0 = __builtin_amdgcn_readfirstlane(ptr[r + 1]);
        float a0 = 0.f, a1 = 0.f, a2 = 0.f, a3 = 0.f;
        int k = s0;
        for (; k + 8 <= e0; k += 8) {
            int c0 = ecol[k],     c1 = ecol[k + 1], c2 = ecol[k + 2], c3 = ecol[k + 3];
            int c4 = ecol[k + 4], c5 = ecol[k + 5], c6 = ecol[k + 6], c7 = ecol[k + 7];
            unsigned char b0 = x8[(size_t)c0 * DDIM + lane];
            unsigned char b1 = x8[(size_t)c1 * DDIM + lane];
            unsigned char b2 = x8[(size_t)c2 * DDIM + lane];
            unsigned char b3 = x8[(size_t)c3 * DDIM + lane];
            unsigned char b4 = x8[(size_t)c4 * DDIM + lane];
            unsigned char b5 = x8[(size_t)c5 * DDIM + lane];
            unsigned char b6 = x8[(size_t)c6 * DDIM + lane];
            unsigned char b7 = x8[(size_t)c7 * DDIM + lane];
            a0 = fmaf(bf2f(eval[k]),     FP8DEC(b0), a0);
            a1 = fmaf(bf2f(eval[k + 1]), FP8DEC(b1), a1);
            a2 = fmaf(bf2f(eval[k + 2]), FP8DEC(b2), a2);
            a3 = fmaf(bf2f(eval[k + 3]), FP8DEC(b3), a3);
            a0 = fmaf(bf2f(eval[k + 4]), FP8DEC(b4), a0);
            a1 = fmaf(bf2f(eval[k + 5]), FP8DEC(b5), a1);
            a2 = fmaf(bf2f(eval[k + 6]), FP8DEC(b6), a2);
            a3 = fmaf(bf2f(eval[k + 7]), FP8DEC(b7), a3);
        }
        for (; k + 4 <= e0; k += 4) {
            int c0 = ecol[k], c1 = ecol[k + 1], c2 = ecol[k + 2], c3 = ecol[k + 3];
            unsigned char b0 = x8[(size_t)c0 * DDIM + lane];
            unsigned char b1 = x8[(size_t)c1 * DDIM + lane];
            unsigned char b2 = x8[(size_t)c2 * DDIM + lane];
            unsigned char b3 = x8[(size_t)c3 * DDIM + lane];
            a0 = fmaf(bf2f(eval[k]),     FP8DEC(b0), a0);
            a1 = fmaf(bf2f(eval[k + 1]), FP8DEC(b1), a1);
            a2 = fmaf(bf2f(eval[k + 2]), FP8DEC(b2), a2);
            a3 = fmaf(bf2f(eval[k + 3]), FP8DEC(b3), a3);
        }
        for (; k < e0; ++k)
            a0 = fmaf(bf2f(eval[k]), FP8DEC(x8[(size_t)ecol[k] * DDIM + lane]), a0);
        float acc = (a0 + a1) + (a2 + a3);
        float bb64 = FP8DEC(base8[(size_t)r * DDIM + lane]);   // 64x true base
        float o = fmaxf(fmaf(bb64, deg[r] * INV64, acc), 0.f);
        if (MODE == 0) {
            (sideB ? out8B : out8A)[(size_t)r * DDIM + lane] = f2fp8(o);
        } else {
            const unsigned char* emb8 = sideB ? emb8B : emb8A;
            float e64 = FP8DEC(emb8[(size_t)r * DDIM + lane]);
            float g = fmaf(add_w[0] * INV64, e64,
                      fmaf(add_w[1] * INV64, bb64, add_w[2] * o));
            (sideB ? outbB : outbA)[(size_t)r * DDIM + lane] = f2bf(g);
            float sq = g * g;
            for (int off = 32; off; off >>= 1) sq += __shfl_down(sq, off);
            if (lane == 0) ssum[wv] = sq;
        }
    } else if (MODE == 1) {
        if (lane == 0) ssum[wv] = 0.f;
    }
    if (MODE == 1) {
        __syncthreads();
        if (threadIdx.x == 0)
            atomicAdd(&(sideB ? accB : accA)[lb & (ACC_SLOTS - 1)],
                      ssum[0] + ssum[1] + ssum[2] + ssum[3]);
    }
}

// ---------------------------------------------------------------------------
// MLP as block-tiled VALU GEMM (unchanged structure)
// ---------------------------------------------------------------------------
__global__ __launch_bounds__(256) void mlp_k(
    const int* __restrict__ user0, const int* __restrict__ item0,
    const unsigned short* __restrict__ gcnU, const unsigned short* __restrict__ gcnI,
    const float* __restrict__ fw1, const float* __restrict__ fb1,
    const float* __restrict__ fw2, const float* __restrict__ fb2,
    unsigned short* __restrict__ ou, unsigned short* __restrict__ oi)
{
    __shared__ unsigned short xs[64][72];
    __shared__ unsigned short w1s[128][68];
    __shared__ unsigned short w2s[64][140];
    __shared__ unsigned short hs[128][72];
    __shared__ float b1s[128];
    __shared__ float b2s[64];

    int t = threadIdx.x;
    int side = blockIdx.x >> 9;
    int tile = blockIdx.x & 511;
    const int* sel = side ? item0 : user0;
    const unsigned short* gcn = side ? gcnI : gcnU;
    unsigned short* outp = side ? oi : ou;

    {
        int r = t >> 2, c = t & 3;
        int idx = sel[tile * 64 + r];
        const ushort4* src = (const ushort4*)(gcn + (size_t)idx * 64 + c * 16);
        ushort4 v0 = src[0], v1 = src[1], v2 = src[2], v3 = src[3];
        int k0 = c * 16;
        xs[k0 +  0][r] = v0.x; xs[k0 +  1][r] = v0.y; xs[k0 +  2][r] = v0.z; xs[k0 +  3][r] = v0.w;
        xs[k0 +  4][r] = v1.x; xs[k0 +  5][r] = v1.y; xs[k0 +  6][r] = v1.z; xs[k0 +  7][r] = v1.w;
        xs[k0 +  8][r] = v2.x; xs[k0 +  9][r] = v2.y; xs[k0 + 10][r] = v2.z; xs[k0 + 11][r] = v2.w;
        xs[k0 + 12][r] = v3.x; xs[k0 + 13][r] = v3.y; xs[k0 + 14][r] = v3.z; xs[k0 + 15][r] = v3.w;
    }
#pragma unroll
    for (int i = 0; i < 8; ++i) {
        int flat = i * 1024 + t * 4;
        float4 w = *(const float4*)(fw1 + flat);
        int o = flat >> 6, k = flat & 63;
        *(unsigned*)&w1s[o][k]     = (unsigned)f2bf(w.x) | ((unsigned)f2bf(w.y) << 16);
        *(unsigned*)&w1s[o][k + 2] = (unsigned)f2bf(w.z) | ((unsigned)f2bf(w.w) << 16);
        float4 u = *(const float4*)(fw2 + flat);
        int o2 = flat >> 7, k2 = flat & 127;
        *(unsigned*)&w2s[o2][k2]     = (unsigned)f2bf(u.x) | ((unsigned)f2bf(u.y) << 16);
        *(unsigned*)&w2s[o2][k2 + 2] = (unsigned)f2bf(u.z) | ((unsigned)f2bf(u.w) << 16);
    }
    if (t < 128) b1s[t] = fb1[t];
    if (t < 64)  b2s[t] = fb2[t];
    __syncthreads();

    int sg = t & 15, og = t >> 4;

    float acc[4][8];
#pragma unroll
    for (int i = 0; i < 4; ++i)
#pragma unroll
        for (int j = 0; j < 8; ++j) acc[i][j] = 0.f;

    for (int kc = 0; kc < 64; kc += 4) {
        uint2 xp0 = *(const uint2*)&xs[kc    ][sg * 4];
        uint2 xp1 = *(const uint2*)&xs[kc + 1][sg * 4];
        uint2 xp2 = *(const uint2*)&xs[kc + 2][sg * 4];
        uint2 xp3 = *(const uint2*)&xs[kc + 3][sg * 4];
        float x0[4] = { bflo(xp0.x), bfhi(xp0.x), bflo(xp0.y), bfhi(xp0.y) };
        float x1[4] = { bflo(xp1.x), bfhi(xp1.x), bflo(xp1.y), bfhi(xp1.y) };
        float x2[4] = { bflo(xp2.x), bfhi(xp2.x), bflo(xp2.y), bfhi(xp2.y) };
        float x3[4] = { bflo(xp3.x), bfhi(xp3.x), bflo(xp3.y), bfhi(xp3.y) };
#pragma unroll
        for (int j = 0; j < 8; ++j) {
            uint2 wp = *(const uint2*)&w1s[og * 8 + j][kc];
            float w0 = bflo(wp.x), w1v = bfhi(wp.x), w2v = bflo(wp.y), w3v = bfhi(wp.y);
#pragma unroll
            for (int i = 0; i < 4; ++i) {
                acc[i][j] = fmaf(x0[i], w0,  acc[i][j]);
                acc[i][j] = fmaf(x1[i], w1v, acc[i][j]);
                acc[i][j] = fmaf(x2[i], w2v, acc[i][j]);
                acc[i][j] = fmaf(x3[i], w3v, acc[i][j]);
            }
        }
    }
#pragma unroll
    for (int j = 0; j < 8; ++j) {
        int o = og * 8 + j;
        float b = b1s[o];
        float h0 = leaky(acc[0][j] + b), h1 = leaky(acc[1][j] + b);
        float h2 = leaky(acc[2][j] + b), h3 = leaky(acc[3][j] + b);
        *(unsigned*)&hs[o][sg * 4]     = (unsigned)f2bf(h0) | ((unsigned)f2bf(h1) << 16);
        *(unsigned*)&hs[o][sg * 4 + 2] = (unsigned)f2bf(h2) | ((unsigned)f2bf(h3) << 16);
    }
    __syncthreads();

    float acc2[4][4];
#pragma unroll
    for (int i = 0; i < 4; ++i)
#pragma unroll
        for (int j = 0; j < 4; ++j) acc2[i][j] = 0.f;

    for (int kc = 0; kc < 128; kc += 4) {
        uint2 hp0 = *(const uint2*)&hs[kc    ][sg * 4];
        uint2 hp1 = *(const uint2*)&hs[kc + 1][sg * 4];
        uint2 hp2 = *(const uint2*)&hs[kc + 2][sg * 4];
        uint2 hp3 = *(const uint2*)&hs[kc + 3][sg * 4];
        float h0[4] = { bflo(hp0.x), bfhi(hp0.x), bflo(hp0.y), bfhi(hp0.y) };
        float h1[4] = { bflo(hp1.x), bfhi(hp1.x), bflo(hp1.y), bfhi(hp1.y) };
        float h2[4] = { bflo(hp2.x), bfhi(hp2.x), bflo(hp2.y), bfhi(hp2.y) };
        float h3[4] = { bflo(hp3.x), bfhi(hp3.x), bflo(hp3.y), bfhi(hp3.y) };
#pragma unroll
        for (int j = 0; j < 4; ++j) {
            uint2 wp = *(const uint2*)&w2s[og * 4 + j][kc];
            float w0 = bflo(wp.x), w1v = bfhi(wp.x), w2v = bflo(wp.y), w3v = bfhi(wp.y);
#pragma unroll
            for (int i = 0; i < 4; ++i) {
                acc2[i][j] = fmaf(h0[i], w0,  acc2[i][j]);
                acc2[i][j] = fmaf(h1[i], w1v, acc2[i][j]);
                acc2[i][j] = fmaf(h2[i], w2v, acc2[i][j]);
                acc2[i][j] = fmaf(h3[i], w3v, acc2[i][j]);
            }
        }
    }
#pragma unroll
    for (int i = 0; i < 4; ++i) {
        float o0 = leaky(acc2[i][0] + b2s[og * 4 + 0]);
        float o1 = leaky(acc2[i][1] + b2s[og * 4 + 1]);
        float o2 = leaky(acc2[i][2] + b2s[og * 4 + 2]);
        float o3 = leaky(acc2[i][3] + b2s[og * 4 + 3]);
        uint2 pp;
        pp.x = (unsigned)f2bf(o0) | ((unsigned)f2bf(o1) << 16);
        pp.y = (unsigned)f2bf(o2) | ((unsigned)f2bf(o3) << 16);
        *(uint2*)(outp + ((size_t)(tile * 64 + sg * 4 + i) * 64 + og * 4)) = pp;
    }
}

// ---------------------------------------------------------------------------
__global__ __launch_bounds__(256) void dot_sse_k(
    const unsigned short* __restrict__ ou, const unsigned short* __restrict__ oi,
    const int* __restrict__ user0, const int* __restrict__ item0,
    const float* __restrict__ ub, const float* __restrict__ ib,
    const float* __restrict__ avg, const float* __restrict__ ratings,
    float* __restrict__ sse)
{
    int g = blockIdx.x * 256 + threadIdx.x;
    int b = g >> 2, q = g & 3;
    const uint4* pu = (const uint4*)(ou + (size_t)b * 64 + q * 16);
    const uint4* pi = (const uint4*)(oi + (size_t)b * 64 + q * 16);
    uint4 a0 = pu[0], a1 = pu[1];
    uint4 c0 = pi[0], c1 = pi[1];
    float s = 0.f;
#define DOTP(ua, uc) { s = fmaf(bflo(ua), bflo(uc), s); s = fmaf(bfhi(ua), bfhi(uc), s); }
    DOTP(a0.x, c0.x) DOTP(a0.y, c0.y) DOTP(a0.z, c0.z) DOTP(a0.w, c0.w)
    DOTP(a1.x, c1.x) DOTP(a1.y, c1.y) DOTP(a1.z, c1.z) DOTP(a1.w, c1.w)
#undef DOTP
    s += __shfl_xor(s, 1);
    s += __shfl_xor(s, 2);
    float contrib = 0.f;
    if (q == 0) {
        float pred = s + ub[user0[b]] + ib[item0[b]] + avg[0];
        float d = pred - ratings[b];
        contrib = d * d;
    }
    for (int off = 32; off; off >>= 1) contrib += __shfl_down(contrib, off);
    __shared__ float wsum[4];
    int lane = threadIdx.x & 63, wv = threadIdx.x >> 6;
    if (lane == 0) wsum[wv] = contrib;
    __syncthreads();
    if (threadIdx.x == 0)
        atomicAdd(sse, wsum[0] + wsum[1] + wsum[2] + wsum[3]);
}

__global__ __launch_bounds__(256) void finalize2_k(
    const float* __restrict__ accU, const float* __restrict__ accI,
    const float* __restrict__ sse, float* __restrict__ out)
{
    int t = threadIdx.x;
    float su = 0.f, si = 0.f;
    for (int i = t; i < ACC_SLOTS; i += 256) { su += accU[i]; si += accI[i]; }
    for (int off = 32; off; off >>= 1) {
        su += __shfl_down(su, off);
        si += __shfl_down(si, off);
    }
    __shared__ float s[8];
    int wv = t >> 6, lane = t & 63;
    if (lane == 0) { s[wv] = su; s[wv + 4] = si; }
    __syncthreads();
    if (t == 0) {
        float SU = s[0] + s[1] + s[2] + s[3];
        float SI = s[4] + s[5] + s[6] + s[7];
        out[0] = sse[0] / (float)BATCH
               + LAM_F * (SU / (float)((double)U_NUM * 64.0))
               + LAM_F * (SI / (float)((double)I_NUM * 64.0));
    }
}

// ---------------------------------------------------------------------------

extern "C" void kernel_launch(void* const* d_in, const int* in_sizes, int n_in,
                              void* d_out, int out_size, void* d_ws, size_t ws_size,
                              hipStream_t stream)
{
    const int*   ui_rows = (const int*)d_in[0];
    const int*   ui_cols = (const int*)d_in[1];
    const float* ui_vals = (const float*)d_in[2];
    const float* iu_vals = (const float*)d_in[3];
    const float* d_i     = (const float*)d_in[4];
    const float* d_j     = (const float*)d_in[5];
    const float* eu      = (const float*)d_in[6];
    const float* ei      = (const float*)d_in[7];
    const float* add_w   = (const float*)d_in[8];
    const float* fw1     = (const float*)d_in[9];
    const float* fb1     = (const float*)d_in[10];
    const float* fw2     = (const float*)d_in[11];
    const float* fb2     = (const float*)d_in[12];
    const float* ub      = (const float*)d_in[13];
    const float* ib      = (const float*)d_in[14];
    const float* avg     = (const float*)d_in[15];
    const int*   user0   = (const int*)d_in[16];
    const int*   item0   = (const int*)d_in[17];
    const float* ratings = (const float*)d_in[18];

    const size_t U64 = (size_t)U_NUM * DDIM;
    const size_t I64 = (size_t)I_NUM * DDIM;

    // ---- workspace layout (~227 MB) ----
    int*            ecol_u = (int*)d_ws;                         // NNZ
    unsigned short* eval_u = (unsigned short*)(ecol_u + NNZ_N);  // NNZ
    int*            ecol_i = (int*)(eval_u + NNZ_N);             // NNZ
    unsigned short* eval_i = (unsigned short*)(ecol_i + NNZ_N);  // NNZ
    // ou/oi overlay ecol_u after the layer-2 SpMM (mlp writes, dot reads)
    unsigned short* ou_bf  = (unsigned short*)ecol_u;            // BATCH*64
    unsigned short* oi_bf  = ou_bf + (size_t)BATCH * 64;
    unsigned*       tc_u   = (unsigned*)(eval_i + NNZ_N);        // NNZ
    unsigned short* tv_u   = (unsigned short*)(tc_u + NNZ_N);    // NNZ
    unsigned*       tc_i   = (unsigned*)(tv_u + NNZ_N);          // NNZ
    unsigned short* tv_i   = (unsigned short*)(tc_i + NNZ_N);    // NNZ
    // g1 fp8 buffers overlay the tmp region (dead after l2sort)
    unsigned char*  g1u_f8 = (unsigned char*)tc_u;               // U64 B
    unsigned char*  g1i_f8 = g1u_f8 + ((U64 + 15) & ~15ull);     // I64 B
    int*  gh_u  = (int*)(tv_i + NNZ_N);                          // NB_U*NBLK
    int*  gh_i  = gh_u + (size_t)NB_U * NBLK;                    // NB_I*NBLK
    int*  bsumU = gh_i + (size_t)NB_I * NBLK;                    // 512
    int*  bsumI = bsumU + 512;                                   // 512
    int*  ptr_u = bsumI + 512;                                   // U+1
    int*  ptr_i = ptr_u + (U_NUM + 1);                           // I+1
    float* accU = (float*)(ptr_i + (I_NUM + 1));                 // ACC_SLOTS
    float* accI = accU + ACC_SLOTS;                              // ACC_SLOTS
    float* sse  = accI + ACC_SLOTS;                              // 4
    unsigned char*  eu_f8  = (unsigned char*)(sse + 4);          // U64 B
    unsigned char*  ei_f8  = eu_f8 + ((U64 + 15) & ~15ull);      // I64 B
    unsigned short* gcnU_bf = (unsigned short*)(ei_f8 + ((I64 + 15) & ~15ull)); // U64
    unsigned short* gcnI_bf = gcnU_bf + U64;                     // I64
    (void)ws_size;

    dim3 blk(256);
    int gu = (U_NUM + 3) / 4, gi = (I_NUM + 3) / 4;
    int nUe = NB_U * NBLK, nIe = NB_I * NBLK;
    int nb1U = (nUe + 1023) / 1024, nb1I = (nIe + 1023) / 1024;

    // zero hist + acc region (gh_u .. sse+4 contiguous)
    size_t meta_bytes = ((char*)(sse + 4)) - (char*)gh_u;
    hipMemsetAsync(gh_u, 0, meta_bytes, stream);

    f2f8_k<<<2048, blk, 0, stream>>>((const float4*)eu, (uchar4*)eu_f8,
                                     (const float4*)ei, (uchar4*)ei_f8,
                                     U64 / 4, (U64 + I64) / 4);

    hist2_k<<<2 * NBLK, blk, 0, stream>>>(ui_rows, ui_cols, gh_u, gh_i);
    scan1m_k<<<nb1U + nb1I, blk, 0, stream>>>(gh_u, nUe, bsumU, nb1U, gh_i, nIe, bsumI);
    scan2m_k<<<2, 512, 0, stream>>>(bsumU, nb1U, bsumI, nb1I);
    scan3m_k<<<nb1U + nb1I, blk, 0, stream>>>(gh_u, nUe, bsumU, nb1U, gh_i, nIe, bsumI);

    scat2_k<<<2 * NBLK, blk, 0, stream>>>(ui_rows, ui_cols, ui_vals, iu_vals,
                                          gh_u, gh_i, tc_u, tv_u, tc_i, tv_i);
    l2sort2_k<<<NB_U + NB_I, blk, 0, stream>>>(tc_u, tv_u, tc_i, tv_i, gh_u, gh_i,
                                               ptr_u, ptr_i, ecol_u, eval_u, ecol_i, eval_i);
    // tmp region dead: g1u_f8 / g1i_f8 overlay it.

    // layer 1: g1 = relu(A@e + e*deg), fp8 out only
    spmm_dual_k<0><<<gu + gi, blk, 0, stream>>>(gu,
        ptr_u, ecol_u, eval_u, ei_f8, eu_f8, d_i, U_NUM, g1u_f8, nullptr, nullptr, nullptr,
        ptr_i, ecol_i, eval_i, eu_f8, ei_f8, d_j, I_NUM, g1i_f8, nullptr, nullptr, nullptr,
        nullptr);
    // layer 2 + combine + fused L2 partials (bf16 gcn out)
    spmm_dual_k<1><<<gi + gu, blk, 0, stream>>>(gi,
        ptr_i, ecol_i, eval_i, g1u_f8, g1i_f8, d_j, I_NUM, nullptr, gcnI_bf, ei_f8, accI,
        ptr_u, ecol_u, eval_u, g1i_f8, g1u_f8, d_i, U_NUM, nullptr, gcnU_bf, eu_f8, accU,
        add_w);

    mlp_k<<<1024, blk, 0, stream>>>(user0, item0, gcnU_bf, gcnI_bf,
                                    fw1, fb1, fw2, fb2, ou_bf, oi_bf);
    dot_sse_k<<<BATCH * 4 / 256, blk, 0, stream>>>(ou_bf, oi_bf, user0, item0,
                                                   ub, ib, avg, ratings, sse);
    finalize2_k<<<1, blk, 0, stream>>>(accU, accI, sse, (float*)d_out);
}